// Round 9
// baseline (546.722 us; speedup 1.0000x reference)
//
#include <hip/hip_runtime.h>
#include <math.h>

#define TOK 4096
#define DM 1024
#define DFF 4096
#define MATSZ 4194304   // 4096*1024 elements per expert matrix
#define PADROWS 9216
#define PADTILES 72

typedef unsigned short u16;
typedef unsigned int   u32;
typedef __attribute__((ext_vector_type(8))) __bf16 bf16x8;
typedef __attribute__((ext_vector_type(4))) float  f32x4;
typedef __attribute__((ext_vector_type(4))) int    i32x4;
typedef __attribute__((ext_vector_type(4))) float  f4v;

#define GLD16(gp, lp) __builtin_amdgcn_global_load_lds( \
    (const __attribute__((address_space(1))) void*)(gp), \
    (__attribute__((address_space(3))) void*)(lp), 16, 0, 0)

// ---------------- helpers ----------------
__device__ __forceinline__ float b2f(u16 u){ return __uint_as_float(((u32)u)<<16); }
__device__ __forceinline__ u16 f2b(float f){
  u32 i = __float_as_uint(f);
  u32 r = i + 0x7fffu + ((i>>16)&1u);
  return (u16)(r>>16);
}
__device__ __forceinline__ void unpack8(uint4 rw, float* dst){
  u32 u0=rw.x,u1=rw.y,u2=rw.z,u3=rw.w;
  dst[0]=__uint_as_float(u0<<16); dst[1]=__uint_as_float(u0&0xffff0000u);
  dst[2]=__uint_as_float(u1<<16); dst[3]=__uint_as_float(u1&0xffff0000u);
  dst[4]=__uint_as_float(u2<<16); dst[5]=__uint_as_float(u2&0xffff0000u);
  dst[6]=__uint_as_float(u3<<16); dst[7]=__uint_as_float(u3&0xffff0000u);
}
__device__ __forceinline__ float block_reduce_sum256(float v, float* red){
  #pragma unroll
  for (int off=32; off>0; off>>=1) v += __shfl_down(v, off);
  __syncthreads();
  if ((threadIdx.x & 63)==0) red[threadIdx.x>>6] = v;
  __syncthreads();
  return red[0]+red[1]+red[2]+red[3];
}
__device__ __forceinline__ float block_reduce_max256(float v, float* red){
  #pragma unroll
  for (int off=32; off>0; off>>=1) v = fmaxf(v, __shfl_down(v, off));
  __syncthreads();
  if ((threadIdx.x & 63)==0) red[threadIdx.x>>6] = v;
  __syncthreads();
  return fmaxf(fmaxf(red[0],red[1]), fmaxf(red[2],red[3]));
}

// ---------------- ternarize (alpha = mean|w| per expert matrix) ----------------
__global__ __launch_bounds__(256) void k_absum1(const float* __restrict__ up, const float* __restrict__ dn,
                                                float* __restrict__ partials){
  const int b = blockIdx.x;                 // 8192 blocks; 512 per matrix
  const size_t f4i = (size_t)b*2048;
  const f4v* s4 = (b < 4096) ? ((const f4v*)up + f4i) : ((const f4v*)dn + (f4i - 8388608));
  const int tid = threadIdx.x;
  float a0=0.f,a1=0.f,a2=0.f,a3=0.f;
  #pragma unroll
  for (int i=0;i<2;i++){
    f4v v0 = __builtin_nontemporal_load(s4 + i*1024 + tid);
    f4v v1 = __builtin_nontemporal_load(s4 + i*1024 + tid + 256);
    f4v v2 = __builtin_nontemporal_load(s4 + i*1024 + tid + 512);
    f4v v3 = __builtin_nontemporal_load(s4 + i*1024 + tid + 768);
    a0 += fabsf(v0[0])+fabsf(v0[1])+fabsf(v0[2])+fabsf(v0[3]);
    a1 += fabsf(v1[0])+fabsf(v1[1])+fabsf(v1[2])+fabsf(v1[3]);
    a2 += fabsf(v2[0])+fabsf(v2[1])+fabsf(v2[2])+fabsf(v2[3]);
    a3 += fabsf(v3[0])+fabsf(v3[1])+fabsf(v3[2])+fabsf(v3[3]);
  }
  __shared__ float red[4];
  float tot = block_reduce_sum256((a0+a1)+(a2+a3), red);
  if (tid==0) partials[b]=tot;
}
__global__ void k_absum2(const float* __restrict__ partials, float* __restrict__ thr,
                         int* __restrict__ counts, int* __restrict__ counts2){
  const int t=threadIdx.x;            // 256 threads: 16 per matrix
  const int m=t>>4, k=t&15;
  float s=0.f;
  for (int i=0;i<32;i++) s += partials[m*512 + k + i*16];
  s += __shfl_xor(s,1); s += __shfl_xor(s,2); s += __shfl_xor(s,4); s += __shfl_xor(s,8);
  if (k==0) thr[m]=0.5f*s/4194304.0f;
  if (t>=224 && t<232) counts[t-224]=0;
  if (t>=232 && t<240) counts2[t-232]=0;
}
__global__ __launch_bounds__(256) void k_ternarize(const float* __restrict__ up, const float* __restrict__ dn,
                                                   const float* __restrict__ thr, signed char* __restrict__ tern){
  const int nvec = 16777216; // 67.1M / 4
  for (int i0 = blockIdx.x*1024 + threadIdx.x; i0 < nvec; i0 += gridDim.x*1024){
    const int i1 = i0 + 256, i2 = i0 + 512, i3 = i0 + 768;
    f4v w0 = (i0 < 8388608) ? __builtin_nontemporal_load((const f4v*)up + i0) : __builtin_nontemporal_load((const f4v*)dn + (i0-8388608));
    f4v w1 = (i1 < 8388608) ? __builtin_nontemporal_load((const f4v*)up + i1) : __builtin_nontemporal_load((const f4v*)dn + (i1-8388608));
    f4v w2 = (i2 < 8388608) ? __builtin_nontemporal_load((const f4v*)up + i2) : __builtin_nontemporal_load((const f4v*)dn + (i2-8388608));
    f4v w3 = (i3 < 8388608) ? __builtin_nontemporal_load((const f4v*)up + i3) : __builtin_nontemporal_load((const f4v*)dn + (i3-8388608));
    float t0 = thr[(int)(((size_t)i0*4)>>22)];
    float t1 = thr[(int)(((size_t)i1*4)>>22)];
    float t2 = thr[(int)(((size_t)i2*4)>>22)];
    float t3 = thr[(int)(((size_t)i3*4)>>22)];
    char4 c0, c1, c2, c3;
    c0.x=(fabsf(w0[0])>t0)?(w0[0]>0.f?1:-1):0; c0.y=(fabsf(w0[1])>t0)?(w0[1]>0.f?1:-1):0;
    c0.z=(fabsf(w0[2])>t0)?(w0[2]>0.f?1:-1):0; c0.w=(fabsf(w0[3])>t0)?(w0[3]>0.f?1:-1):0;
    c1.x=(fabsf(w1[0])>t1)?(w1[0]>0.f?1:-1):0; c1.y=(fabsf(w1[1])>t1)?(w1[1]>0.f?1:-1):0;
    c1.z=(fabsf(w1[2])>t1)?(w1[2]>0.f?1:-1):0; c1.w=(fabsf(w1[3])>t1)?(w1[3]>0.f?1:-1):0;
    c2.x=(fabsf(w2[0])>t2)?(w2[0]>0.f?1:-1):0; c2.y=(fabsf(w2[1])>t2)?(w2[1]>0.f?1:-1):0;
    c2.z=(fabsf(w2[2])>t2)?(w2[2]>0.f?1:-1):0; c2.w=(fabsf(w2[3])>t2)?(w2[3]>0.f?1:-1):0;
    c3.x=(fabsf(w3[0])>t3)?(w3[0]>0.f?1:-1):0; c3.y=(fabsf(w3[1])>t3)?(w3[1]>0.f?1:-1):0;
    c3.z=(fabsf(w3[2])>t3)?(w3[2]>0.f?1:-1):0; c3.w=(fabsf(w3[3])>t3)?(w3[3]>0.f?1:-1):0;
    *(char4*)(tern+(size_t)i0*4) = c0;
    *(char4*)(tern+(size_t)i1*4) = c1;
    *(char4*)(tern+(size_t)i2*4) = c2;
    *(char4*)(tern+(size_t)i3*4) = c3;
  }
}
__global__ __launch_bounds__(256) void k_f2b(const float* __restrict__ s, u16* __restrict__ d, int n4){
  int i = blockIdx.x*256+threadIdx.x;
  if (i<n4){
    float4 v=((const float4*)s)[i];
    ushort4 o; o.x=f2b(v.x); o.y=f2b(v.y); o.z=f2b(v.z); o.w=f2b(v.w);
    ((ushort4*)d)[i]=o;
  }
}

// ---------------- layernorm 1 ----------------
__global__ __launch_bounds__(256) void k_ln1(const float* __restrict__ x, const float* __restrict__ g,
                                             const float* __restrict__ b, u16* __restrict__ h){
  __shared__ float red[4];
  const int t=blockIdx.x, tid=threadIdx.x;
  float4 xv = ((const float4*)(x + (size_t)t*DM))[tid];
  float s  = xv.x+xv.y+xv.z+xv.w;
  float sq = xv.x*xv.x+xv.y*xv.y+xv.z*xv.z+xv.w*xv.w;
  float sum  = block_reduce_sum256(s, red);
  float sums = block_reduce_sum256(sq, red);
  float mu = sum*(1.0f/DM);
  float var = sums*(1.0f/DM) - mu*mu;
  float rstd = rsqrtf(var+1e-5f);
  float4 gv = ((const float4*)g)[tid];
  float4 bv = ((const float4*)b)[tid];
  ushort4 pk;
  pk.x = f2b((xv.x-mu)*rstd*gv.x+bv.x);
  pk.y = f2b((xv.y-mu)*rstd*gv.y+bv.y);
  pk.z = f2b((xv.z-mu)*rstd*gv.z+bv.z);
  pk.w = f2b((xv.w-mu)*rstd*gv.w+bv.w);
  ((ushort4*)(h + (size_t)t*DM))[tid] = pk;
}

// ---------------- bf16 MFMA GEMM: 128x128, BK=32, depth-2 prefetch (3 buffers, counted vmcnt) ----------------
// Per iter: wait vmcnt(4) [stage(t) done, stage(t+1) in flight] -> barrier -> issue stage(t+2) -> compute.
// Steady state never drains to vmcnt(0); stage gets 2 iterations of flight (T4 pattern).
template<int MODE>
__global__ __launch_bounds__(256) void k_gemm(const u16* __restrict__ A, const u16* __restrict__ B,
                                              int K, int ldc, const float* __restrict__ bias,
                                              const float* __restrict__ resid, void* __restrict__ Cout,
                                              u16* __restrict__ vT){
  __shared__ u16 As[3][128*32];
  __shared__ u16 Bs[3][128*32];
  const int tid = threadIdx.x;
  const int w = tid>>6, lane = tid&63;
  const int m0 = blockIdx.y*128, n0 = blockIdx.x*128;

  const int sr = lane>>2, ss = lane&3;
  const int ra0 = w*32 + sr, ra1 = ra0 + 16;
  const int kb0 = (ss ^ ((ra0>>1)&3))<<3;
  const int kb1 = (ss ^ ((ra1>>1)&3))<<3;
  const u16* pa0 = A + (size_t)(m0+ra0)*K + kb0;
  const u16* pa1 = A + (size_t)(m0+ra1)*K + kb1;
  const u16* pb0 = B + (size_t)(n0+ra0)*K + kb0;
  const u16* pb1 = B + (size_t)(n0+ra1)*K + kb1;
  const int lo0 = (w*32)*32, lo1 = lo0 + 16*32;

  const int wm = w>>1, wn = w&1;
  const int lr = lane&15, sl = lane>>4;
  int offA[4], offB[4];
  #pragma unroll
  for (int m=0;m<4;m++){ int r = wm*64 + m*16 + lr; offA[m] = r*64 + ((sl ^ ((r>>1)&3))<<4); }
  #pragma unroll
  for (int n=0;n<4;n++){ int r = wn*64 + n*16 + lr; offB[n] = r*64 + ((sl ^ ((r>>1)&3))<<4); }

  f32x4 acc[4][4] = {};
  const int NT = K>>5;
  // prologue: stage tiles 0 and 1
  GLD16(pa0, &As[0][lo0]); GLD16(pa1, &As[0][lo1]);
  GLD16(pb0, &Bs[0][lo0]); GLD16(pb1, &Bs[0][lo1]);
  pa0+=32; pa1+=32; pb0+=32; pb1+=32;
  GLD16(pa0, &As[1][lo0]); GLD16(pa1, &As[1][lo1]);
  GLD16(pb0, &Bs[1][lo0]); GLD16(pb1, &Bs[1][lo1]);
  pa0+=32; pa1+=32; pb0+=32; pb1+=32;

  int cur=0, nx2=2;
  for (int t=0;t<NT;t++){
    if (t+1<NT) asm volatile("s_waitcnt vmcnt(4) lgkmcnt(0)" ::: "memory");
    else        asm volatile("s_waitcnt vmcnt(0) lgkmcnt(0)" ::: "memory");
    __builtin_amdgcn_s_barrier();
    if (t+2<NT){
      GLD16(pa0, &As[nx2][lo0]); GLD16(pa1, &As[nx2][lo1]);
      GLD16(pb0, &Bs[nx2][lo0]); GLD16(pb1, &Bs[nx2][lo1]);
      pa0+=32; pa1+=32; pb0+=32; pb1+=32;
    }
    const char* Ab = (const char*)As[cur];
    const char* Bb = (const char*)Bs[cur];
    bf16x8 af[4], bfv[4];
    #pragma unroll
    for (int m=0;m<4;m++) af[m] = *(const bf16x8*)(Ab + offA[m]);
    #pragma unroll
    for (int n=0;n<4;n++) bfv[n] = *(const bf16x8*)(Bb + offB[n]);
    #pragma unroll
    for (int m=0;m<4;m++)
      #pragma unroll
      for (int n=0;n<4;n++)
        acc[m][n] = __builtin_amdgcn_mfma_f32_16x16x32_bf16(af[m], bfv[n], acc[m][n], 0, 0, 0);
    cur = (cur==2)?0:cur+1;
    nx2 = (nx2==2)?0:nx2+1;
  }

  const int rowg = lane>>4;
  #pragma unroll
  for (int m=0;m<4;m++){
    const int rbase = m0 + wm*64 + m*16 + rowg*4;
    #pragma unroll
    for (int n=0;n<4;n++){
      const int col = n0 + wn*64 + n*16 + lr;
      if (MODE==2){
        u16 pk4[4];
        #pragma unroll
        for (int j=0;j<4;j++){
          float v = acc[m][n][j] + bias[col];
          pk4[j] = f2b(v);
          ((u16*)Cout)[(size_t)(rbase+j)*ldc + col] = pk4[j];
        }
        if (col >= 2048){
          const int d = col-2048, hd = d>>6, dd = d&63;
          const int bb = rbase>>10, s = rbase&1023;
          uint2 pk; pk.x = (u32)pk4[0] | ((u32)pk4[1]<<16); pk.y = (u32)pk4[2] | ((u32)pk4[3]<<16);
          *(uint2*)(vT + (((size_t)((bb*16+hd)*64+dd))<<10) + s) = pk;
        }
      } else {
        #pragma unroll
        for (int j=0;j<4;j++){
          const size_t ci = (size_t)(rbase+j)*ldc + col;
          ((float*)Cout)[ci] = acc[m][n][j] + bias[col] + resid[ci];
        }
      }
    }
  }
}

// ---------------- i8 MFMA GEMM for MoE, depth-2 prefetch (3 buffers, counted vmcnt) ----------------
template<bool GATHER>
__global__ __launch_bounds__(256) void k_gemm8(const signed char* __restrict__ A, const signed char* __restrict__ Ball,
                                               int K, int ldc,
                                               const int* __restrict__ tile2e, const int* __restrict__ rowmap,
                                               const float* __restrict__ rscale, u16* __restrict__ Cout){
  int e = tile2e[blockIdx.y];
  if (e < 0) return;
  const signed char* Bp = Ball + (size_t)e * MATSZ;
  __shared__ signed char As[3][128*64];
  __shared__ signed char Bs[3][128*64];
  const int tid = threadIdx.x;
  const int w = tid>>6, lane = tid&63;
  const int m0 = blockIdx.y*128, n0 = blockIdx.x*128;

  const int sr = lane>>2, ss = lane&3;
  const int ra0 = w*32 + sr, ra1 = ra0 + 16;
  const int kb0 = (ss ^ ((ra0>>1)&3))<<4;   // byte offset of 16B slot
  const int kb1 = (ss ^ ((ra1>>1)&3))<<4;
  const signed char *pa0, *pa1;
  if (GATHER){
    int t0 = rowmap[m0+ra0]; if (t0<0) t0 = 0;
    int t1 = rowmap[m0+ra1]; if (t1<0) t1 = 0;
    pa0 = A + (size_t)t0*K + kb0;
    pa1 = A + (size_t)t1*K + kb1;
  } else {
    pa0 = A + (size_t)(m0+ra0)*K + kb0;
    pa1 = A + (size_t)(m0+ra1)*K + kb1;
  }
  const signed char* pb0 = Bp + (size_t)(n0+ra0)*K + kb0;
  const signed char* pb1 = Bp + (size_t)(n0+ra1)*K + kb1;
  const int lo0 = (w*32)*64, lo1 = lo0 + 16*64;

  const int wm = w>>1, wn = w&1;
  const int lr = lane&15, sl = lane>>4;
  int offA[4], offB[4];
  #pragma unroll
  for (int m=0;m<4;m++){ int r = wm*64 + m*16 + lr; offA[m] = r*64 + ((sl ^ ((r>>1)&3))<<4); }
  #pragma unroll
  for (int n=0;n<4;n++){ int r = wn*64 + n*16 + lr; offB[n] = r*64 + ((sl ^ ((r>>1)&3))<<4); }

  i32x4 acc[4][4] = {};
  const int NT = K>>6;
  GLD16(pa0, &As[0][lo0]); GLD16(pa1, &As[0][lo1]);
  GLD16(pb0, &Bs[0][lo0]); GLD16(pb1, &Bs[0][lo1]);
  pa0+=64; pa1+=64; pb0+=64; pb1+=64;
  GLD16(pa0, &As[1][lo0]); GLD16(pa1, &As[1][lo1]);
  GLD16(pb0, &Bs[1][lo0]); GLD16(pb1, &Bs[1][lo1]);
  pa0+=64; pa1+=64; pb0+=64; pb1+=64;

  int cur=0, nx2=2;
  for (int t=0;t<NT;t++){
    if (t+1<NT) asm volatile("s_waitcnt vmcnt(4) lgkmcnt(0)" ::: "memory");
    else        asm volatile("s_waitcnt vmcnt(0) lgkmcnt(0)" ::: "memory");
    __builtin_amdgcn_s_barrier();
    if (t+2<NT){
      GLD16(pa0, &As[nx2][lo0]); GLD16(pa1, &As[nx2][lo1]);
      GLD16(pb0, &Bs[nx2][lo0]); GLD16(pb1, &Bs[nx2][lo1]);
      pa0+=64; pa1+=64; pb0+=64; pb1+=64;
    }
    const char* Ab = (const char*)As[cur];
    const char* Bb = (const char*)Bs[cur];
    i32x4 af[4], bfv[4];
    #pragma unroll
    for (int m=0;m<4;m++) af[m] = *(const i32x4*)(Ab + offA[m]);
    #pragma unroll
    for (int n=0;n<4;n++) bfv[n] = *(const i32x4*)(Bb + offB[n]);
    #pragma unroll
    for (int m=0;m<4;m++)
      #pragma unroll
      for (int n=0;n<4;n++)
        acc[m][n] = __builtin_amdgcn_mfma_i32_16x16x64_i8(af[m], bfv[n], acc[m][n], 0, 0, 0);
    cur = (cur==2)?0:cur+1;
    nx2 = (nx2==2)?0:nx2+1;
  }

  const int rowg = lane>>4;
  #pragma unroll
  for (int m=0;m<4;m++){
    const int rbase = m0 + wm*64 + m*16 + rowg*4;
    #pragma unroll
    for (int n=0;n<4;n++){
      const int col = n0 + wn*64 + n*16 + lr;
      #pragma unroll
      for (int j=0;j<4;j++){
        float v = (float)acc[m][n][j] * rscale[rbase+j];
        Cout[(size_t)(rbase+j)*ldc + col] = f2b(v);
      }
    }
  }
}

// ---------------- MFMA flash attention (exp2 + defer-max + dbuf KV + setprio) ----------------
__global__ __launch_bounds__(256) void k_attn_mfma(const u16* __restrict__ qkv, const u16* __restrict__ vT,
                                                   u16* __restrict__ ob){
  __shared__ u16 Ks[2][64*64];
  __shared__ u16 Vs[2][64*64];
  __shared__ u16 Pa[4*16*64];
  const int qt=blockIdx.x, hh=blockIdx.y, bb=blockIdx.z;
  const int tid=threadIdx.x, w=tid>>6, lane=tid&63;
  const int g=lane>>4, lr=lane&15;
  const int srow8=lane>>3, sslot=lane&7;
  const float RTHR = 11.5f;   // log2 units

  bf16x8 qa[2];
  {
    const u16* qp = qkv + ((size_t)(bb*1024 + qt*64 + w*16 + lr))*3072 + hh*64 + g*8;
    #pragma unroll
    for (int c=0;c<2;c++){
      uint4 raw = *(const uint4*)(qp + c*32);
      float tv[8]; unpack8(raw,tv);
      union { u16 s[8]; bf16x8 v; } qq;
      #pragma unroll
      for (int i=0;i<8;i++) qq.s[i] = f2b(tv[i]*0.18033688f);
      qa[c] = qq.v;
    }
  }

  float mrow[4], lrow[4];
  #pragma unroll
  for (int j=0;j<4;j++){ mrow[j]=-1e30f; lrow[j]=0.f; }
  f32x4 acc_o[4] = {};

  char* pbuf = (char*)Pa + (w<<11);

  const int row0 = w*16 + srow8, row1 = row0 + 8;
  const int fs0 = (sslot ^ (row0&7))<<3;
  const int fs1 = (sslot ^ (row1&7))<<3;
  const int ldso0 = (w*16)*64, ldso1 = (w*16+8)*64;

  {
    const u16* gk0 = qkv + ((size_t)(bb*1024 + row0))*3072 + 1024 + hh*64 + fs0;
    const u16* gk1 = qkv + ((size_t)(bb*1024 + row1))*3072 + 1024 + hh*64 + fs1;
    GLD16(gk0, &Ks[0][ldso0]); GLD16(gk1, &Ks[0][ldso1]);
    const u16* gv0 = vT + ((size_t)((bb*16+hh)*64 + row0))*1024 + fs0;
    const u16* gv1 = vT + ((size_t)((bb*16+hh)*64 + row1))*1024 + fs1;
    GLD16(gv0, &Vs[0][ldso0]); GLD16(gv1, &Vs[0][ldso1]);
  }
  __syncthreads();

  for (int kt=0; kt<16; ++kt){
    if (kt+1<16){
      const int nb=(kt+1)&1;
      const u16* gk0 = qkv + ((size_t)(bb*1024 + (kt+1)*64 + row0))*3072 + 1024 + hh*64 + fs0;
      const u16* gk1 = qkv + ((size_t)(bb*1024 + (kt+1)*64 + row1))*3072 + 1024 + hh*64 + fs1;
      GLD16(gk0, &Ks[nb][ldso0]); GLD16(gk1, &Ks[nb][ldso1]);
      const u16* gv0 = vT + ((size_t)((bb*16+hh)*64 + row0))*1024 + (kt+1)*64 + fs0;
      const u16* gv1 = vT + ((size_t)((bb*16+hh)*64 + row1))*1024 + (kt+1)*64 + fs1;
      GLD16(gv0, &Vs[nb][ldso0]); GLD16(gv1, &Vs[nb][ldso1]);
    }
    const char* Kb = (const char*)Ks[kt&1];
    const char* Vb = (const char*)Vs[kt&1];

    f32x4 sacc[4] = {};
    __builtin_amdgcn_s_setprio(1);
    #pragma unroll
    for (int ct=0; ct<4; ct++){
      const int kv = ct*16 + lr;
      const char* krow = Kb + kv*128;
      bf16x8 kb0 = *(const bf16x8*)(krow + (((g  ) ^ (kv&7))<<4));
      bf16x8 kb1 = *(const bf16x8*)(krow + (((4+g) ^ (kv&7))<<4));
      sacc[ct] = __builtin_amdgcn_mfma_f32_16x16x32_bf16(qa[0], kb0, sacc[ct], 0,0,0);
      sacc[ct] = __builtin_amdgcn_mfma_f32_16x16x32_bf16(qa[1], kb1, sacc[ct], 0,0,0);
    }
    __builtin_amdgcn_s_setprio(0);

    float vmx[4]; bool okl = true;
    #pragma unroll
    for (int j=0;j<4;j++){
      vmx[j] = fmaxf(fmaxf(sacc[0][j],sacc[1][j]), fmaxf(sacc[2][j],sacc[3][j]));
      okl = okl && (vmx[j]-mrow[j] <= RTHR);
    }
    float psum[4] = {0.f,0.f,0.f,0.f};
    if (__all((int)okl)){
      #pragma unroll
      for (int ct=0; ct<4; ct++){
        #pragma unroll
        for (int j=0;j<4;j++){
          float p = exp2f(sacc[ct][j]-mrow[j]);
          psum[j] += p;
          const int q = g*4+j, k = ct*16+lr;
          *(u16*)(pbuf + q*128 + (((k>>3) ^ (q&7))<<4) + ((k&7)<<1)) = f2b(p);
        }
      }
      #pragma unroll
      for (int j=0;j<4;j++){
        float s = psum[j];
        s += __shfl_xor(s,1); s += __shfl_xor(s,2); s += __shfl_xor(s,4); s += __shfl_xor(s,8);
        lrow[j] += s;
      }
    } else {
      float mnew[4], corr[4];
      #pragma unroll
      for (int j=0;j<4;j++){
        float v = vmx[j];
        v = fmaxf(v, __shfl_xor(v,1));
        v = fmaxf(v, __shfl_xor(v,2));
        v = fmaxf(v, __shfl_xor(v,4));
        v = fmaxf(v, __shfl_xor(v,8));
        mnew[j] = fmaxf(mrow[j], v);
        corr[j] = exp2f(mrow[j]-mnew[j]);
        mrow[j] = mnew[j];
      }
      #pragma unroll
      for (int ct=0; ct<4; ct++){
        #pragma unroll
        for (int j=0;j<4;j++){
          float p = exp2f(sacc[ct][j]-mrow[j]);
          psum[j] += p;
          const int q = g*4+j, k = ct*16+lr;
          *(u16*)(pbuf + q*128 + (((k>>3) ^ (q&7))<<4) + ((k&7)<<1)) = f2b(p);
        }
      }
      #pragma unroll
      for (int j=0;j<4;j++){
        float s = psum[j];
        s += __shfl_xor(s,1); s += __shfl_xor(s,2); s += __shfl_xor(s,4); s += __shfl_xor(s,8);
        lrow[j] = lrow[j]*corr[j] + s;
      }
      #pragma unroll
      for (int ctd=0; ctd<4; ctd++)
        #pragma unroll
        for (int j=0;j<4;j++) acc_o[ctd][j] *= corr[j];
    }

    __builtin_amdgcn_s_setprio(1);
    #pragma unroll
    for (int c=0;c<2;c++){
      bf16x8 pa = *(const bf16x8*)(pbuf + lr*128 + (((c*4+g) ^ (lr&7))<<4));
      #pragma unroll
      for (int ctd=0; ctd<4; ctd++){
        const int d = ctd*16 + lr;
        bf16x8 vb = *(const bf16x8*)(Vb + d*128 + (((c*4+g) ^ (d&7))<<4));
        acc_o[ctd] = __builtin_amdgcn_mfma_f32_16x16x32_bf16(pa, vb, acc_o[ctd], 0,0,0);
      }
    }
    __builtin_amdgcn_s_setprio(0);
    __syncthreads();
  }

  #pragma unroll
  for (int j=0;j<4;j++){
    const float inv = 1.0f/lrow[j];
    const int row = bb*1024 + qt*64 + w*16 + g*4 + j;
    u16* op = ob + (size_t)row*DM + hh*64 + lr;
    #pragma unroll
    for (int ctd=0; ctd<4; ctd++) op[ctd*16] = f2b(acc_o[ctd][j]*inv);
  }
}

// ---------------- layernorm 2 + geometric router + i8 quant (+fused expert count) ----------------
__global__ __launch_bounds__(256) void k_ln2_router(const float* __restrict__ xa, const float* __restrict__ g,
                                                    const float* __restrict__ b, const float* __restrict__ rw,
                                                    signed char* __restrict__ xn8, int* __restrict__ eidx,
                                                    float* __restrict__ w1o, float* __restrict__ sbc,
                                                    int* __restrict__ counts){
  __shared__ float red[4];
  const int t=blockIdx.x, tid=threadIdx.x;
  float4 xv = ((const float4*)(xa + (size_t)t*DM))[tid];
  float s  = xv.x+xv.y+xv.z+xv.w;
  float sq = xv.x*xv.x+xv.y*xv.y+xv.z*xv.z+xv.w*xv.w;
  float sum  = block_reduce_sum256(s, red);
  float sums = block_reduce_sum256(sq, red);
  float mu = sum*(1.0f/DM);
  float var = sums*(1.0f/DM) - mu*mu;
  float rstd = rsqrtf(var+1e-5f);
  float4 gv = ((const float4*)g)[tid];
  float4 bv = ((const float4*)b)[tid];
  float y0=(xv.x-mu)*rstd*gv.x+bv.x;
  float y1=(xv.y-mu)*rstd*gv.y+bv.y;
  float y2=(xv.z-mu)*rstd*gv.z+bv.z;
  float y3=(xv.w-mu)*rstd*gv.w+bv.w;
  float4 r0=((const float4*)(rw+0*DM))[tid];
  float4 r1=((const float4*)(rw+1*DM))[tid];
  float4 r2=((const float4*)(rw+2*DM))[tid];
  float4 r3=((const float4*)(rw+3*DM))[tid];
  float nsq = y0*y0+y1*y1+y2*y2+y3*y3;
  float d0 = y0*r0.x+y1*r0.y+y2*r0.z+y3*r0.w;
  float d1 = y0*r1.x+y1*r1.y+y2*r1.z+y3*r1.w;
  float d2 = y0*r2.x+y1*r2.y+y2*r2.z+y3*r2.w;
  float d3 = y0*r3.x+y1*r3.y+y2*r3.z+y3*r3.w;
  float am = fmaxf(fmaxf(fabsf(y0),fabsf(y1)), fmaxf(fabsf(y2),fabsf(y3)));
  float AM = block_reduce_max256(am, red);
  float SQ = block_reduce_sum256(nsq, red);
  float D0 = block_reduce_sum256(d0, red);
  float D1 = block_reduce_sum256(d1, red);
  float D2 = block_reduce_sum256(d2, red);
  float D3 = block_reduce_sum256(d3, red);
  float qs = fmaxf(AM, 1e-12f) * (1.0f/127.0f);
  float inv = 1.0f/qs;
  char4 c;
  c.x = (signed char)__float2int_rn(y0*inv);
  c.y = (signed char)__float2int_rn(y1*inv);
  c.z = (signed char)__float2int_rn(y2*inv);
  c.w = (signed char)__float2int_rn(y3*inv);
  ((char4*)(xn8 + (size_t)t*DM))[tid] = c;
  if (tid==0){
    float n = fmaxf(sqrtf(D0*D0+D1*D1+D2*D2+D3*D3), 1e-12f);
    float h0=D0/n, h1=D1/n, h2=D2/n, h3=D3/n;
    float dot0 = 0.70710678f*(h0-h1);
    float dot1 = 0.70710678f*(h1-h2);
    float dot2 = h2;
    float dot3 = (-0.5f*h0+0.5f*h1+0.5f*h2+0.80901699f*h3)*0.8437966f;
    int ch = (int)(dot0>=0.f) + 2*(int)(dot1>=0.f) + 4*(int)(dot2>=0.f) + 8*(int)(dot3>=0.f);
    int e1 = ch & 7;
    int e2 = ((ch>>1)+1) & 7;
    if (e1==e2) e2=(e2+1)&7;
    float conf = fminf(fminf(fabsf(dot0),fabsf(dot1)), fminf(fabsf(dot2),fabsf(dot3)));
    eidx[2*t]=e1; eidx[2*t+1]=e2;
    atomicAdd(&counts[e1],1); atomicAdd(&counts[e2],1);
    w1o[t]=0.5f + 0.3f/(1.0f+__expf(-conf));
    sbc[t]= qs / (sqrtf(SQ*(1.0f/DM))+1e-8f);
  }
}

// ---------------- routing bookkeeping ----------------
__global__ void k_offsets(const int* __restrict__ counts, int* __restrict__ offs, int* __restrict__ tile2e,
                          int* __restrict__ rowmap, float* __restrict__ srow, int* __restrict__ ptot){
  const int tid=threadIdx.x;
  if (tid==0){
    int off=0;
    for (int e=0;e<8;e++){
      offs[e]=off;
      int pad = ((counts[e]+127)>>7)<<7;
      int t0=off>>7, t1=(off+pad)>>7;
      for (int tt=t0;tt<t1;tt++) tile2e[tt]=e;
      off+=pad;
    }
    offs[8]=off; *ptot=off;
    for (int tt=off>>7; tt<PADTILES; tt++) tile2e[tt]=-1;
  }
  for (int i=tid;i<PADROWS;i+=blockDim.x){ rowmap[i]=-1; srow[i]=0.f; }
}
__global__ void k_scatter(const int* __restrict__ eidx, const int* __restrict__ offs, int* __restrict__ counts2,
                          int* __restrict__ rowmap, int* __restrict__ tokrow,
                          const float* __restrict__ sbc, float* __restrict__ srow){
  int t = blockIdx.x*256+threadIdx.x;
  if (t<TOK){
    int e1=eidx[2*t], e2=eidx[2*t+1];
    float s = sbc[t];
    int p1 = atomicAdd(&counts2[e1],1);
    int r1 = offs[e1]+p1; rowmap[r1]=t; srow[r1]=s; tokrow[2*t]=r1;
    int p2 = atomicAdd(&counts2[e2],1);
    int r2 = offs[e2]+p2; rowmap[r2]=t; srow[r2]=s; tokrow[2*t+1]=r2;
  }
}

// ---------------- GELU (exact) + per-row RMS normalize + i8 quant ----------------
__global__ __launch_bounds__(256) void k_gelu_rms(const u16* __restrict__ he, signed char* __restrict__ he8,
                                                  float* __restrict__ qd, const int* __restrict__ ptot){
  const int row = blockIdx.x;
  if (row >= *ptot) return;
  const u16* p = he + (size_t)row*DFF;
  const int tid=threadIdx.x;
  uint4 rw0 = ((const uint4*)p)[2*tid];
  uint4 rw1 = ((const uint4*)p)[2*tid+1];
  float v[16];
  unpack8(rw0, v); unpack8(rw1, v+8);
  float sq=0.f;
  #pragma unroll
  for (int q=0;q<16;q++){
    float xg = v[q];
    float ge = 0.5f*xg*(1.0f+erff(xg*0.70710678f));
    v[q]=ge; sq += ge*ge;
  }
  __shared__ float red[4];
  float SQ = block_reduce_sum256(sq, red);
  float s = 1.0f/(sqrtf(SQ*(1.0f/DFF))+1e-8f);
  float am = 0.f;
  #pragma unroll
  for (int q=0;q<16;q++){ v[q]*=s; am = fmaxf(am, fabsf(v[q])); }
  float AM = block_reduce_max256(am, red);
  float q8 = fmaxf(AM, 1e-12f) * (1.0f/127.0f);
  float inv = 1.0f/q8;
  union { signed char c[16]; uint4 u; } pk;
  #pragma unroll
  for (int q=0;q<16;q++) pk.c[q] = (signed char)__float2int_rn(v[q]*inv);
  ((uint4*)(he8 + (size_t)row*DFF))[tid] = pk.u;
  if (tid==0) qd[row] = q8;
}

// ---------------- combine ----------------
__global__ __launch_bounds__(256) void k_combine(const float* __restrict__ xa, const u16* __restrict__ y,
                                                 const int* __restrict__ tokrow, const float* __restrict__ w1,
                                                 float* __restrict__ out){
  const int t=blockIdx.x, tid=threadIdx.x;
  const int r1=tokrow[2*t], r2=tokrow[2*t+1];
  const float a = w1[t], bw = 1.0f-a;
  float4 xv = ((const float4*)(xa + (size_t)t*DM))[tid];
  ushort4 y1 = ((const ushort4*)(y + (size_t)r1*DM))[tid];
  ushort4 y2 = ((const ushort4*)(y + (size_t)r2*DM))[tid];
  float4 o;
  o.x = xv.x + a*b2f(y1.x) + bw*b2f(y2.x);
  o.y = xv.y + a*b2f(y1.y) + bw*b2f(y2.y);
  o.z = xv.z + a*b2f(y1.z) + bw*b2f(y2.z);
  o.w = xv.w + a*b2f(y1.w) + bw*b2f(y2.w);
  ((float4*)(out + (size_t)t*DM))[tid] = o;
}

extern "C" void kernel_launch(void* const* d_in, const int* in_sizes, int n_in,
                              void* d_out, int out_size, void* d_ws, size_t ws_size,
                              hipStream_t stream){
  (void)in_sizes; (void)n_in; (void)out_size; (void)ws_size;
  const float* x    = (const float*)d_in[0];
  const float* g1   = (const float*)d_in[1];
  const float* b1   = (const float*)d_in[2];
  const float* g2   = (const float*)d_in[3];
  const float* b2   = (const float*)d_in[4];
  const float* in_w = (const float*)d_in[5];
  const float* in_b = (const float*)d_in[6];
  const float* out_w= (const float*)d_in[7];
  const float* out_b= (const float*)d_in[8];
  const float* rw   = (const float*)d_in[9];
  const float* up_w = (const float*)d_in[10];
  const float* dn_w = (const float*)d_in[11];
  float* out = (float*)d_out;

  char* base = (char*)d_ws; size_t off=0;
  auto alloc = [&](size_t bytes)->char*{ char* p = base+off; off=(off+bytes+255)&~(size_t)255; return p; };
  u16* h      = (u16*)alloc((size_t)TOK*DM*2);
  u16* qkv    = (u16*)alloc((size_t)TOK*3072*2);
  u16* ob     = (u16*)alloc((size_t)TOK*DM*2);
  float* xattn= (float*)alloc((size_t)TOK*DM*4);
  signed char* xn8 = (signed char*)alloc((size_t)TOK*DM);
  signed char* tern8 = (signed char*)alloc((size_t)16*MATSZ);
  u16* wbf_in = (u16*)alloc((size_t)3145728*2);
  u16* wbf_out= (u16*)alloc((size_t)1048576*2);
  u16* vT     = (u16*)alloc((size_t)4*16*64*1024*2);
  u16* he     = (u16*)alloc((size_t)PADROWS*DFF*2);
  signed char* he8 = (signed char*)alloc((size_t)PADROWS*DFF);
  u16* y      = (u16*)alloc((size_t)PADROWS*DM*2);
  float* partials = (float*)alloc(8192*4);
  float* thr  = (float*)alloc(64);
  int* counts = (int*)alloc(32);
  int* counts2= (int*)alloc(32);
  int* offs   = (int*)alloc(64);
  int* ptot   = (int*)alloc(64);
  int* eidx   = (int*)alloc((size_t)TOK*2*4);
  float* w1b  = (float*)alloc((size_t)TOK*4);
  float* sbc  = (float*)alloc((size_t)TOK*4);
  float* srow = (float*)alloc((size_t)PADROWS*4);
  float* qd   = (float*)alloc((size_t)PADROWS*4);
  int* tokrow = (int*)alloc((size_t)TOK*2*4);
  int* rowmap = (int*)alloc((size_t)PADROWS*4);
  int* tile2e = (int*)alloc(PADTILES*4);

  k_absum1<<<8192,256,0,stream>>>(up_w, dn_w, partials);
  k_absum2<<<1,256,0,stream>>>(partials, thr, counts, counts2);
  k_ternarize<<<8192,256,0,stream>>>(up_w, dn_w, thr, tern8);
  k_f2b<<<3072,256,0,stream>>>(in_w, wbf_in, 786432);
  k_f2b<<<1024,256,0,stream>>>(out_w, wbf_out, 262144);
  k_ln1<<<TOK,256,0,stream>>>(x, g1, b1, h);
  k_gemm<2><<<dim3(24,32),256,0,stream>>>(h, wbf_in, 1024, 3072, in_b, nullptr, qkv, vT);
  k_attn_mfma<<<dim3(16,16,4),256,0,stream>>>(qkv, vT, ob);
  k_gemm<3><<<dim3(8,32),256,0,stream>>>(ob, wbf_out, 1024, 1024, out_b, x, xattn, nullptr);
  k_ln2_router<<<TOK,256,0,stream>>>(xattn, g2, b2, rw, xn8, eidx, w1b, sbc, counts);
  k_offsets<<<1,256,0,stream>>>(counts, offs, tile2e, rowmap, srow, ptot);
  k_scatter<<<16,256,0,stream>>>(eidx, offs, counts2, rowmap, tokrow, sbc, srow);
  k_gemm8<true><<<dim3(32,PADTILES),256,0,stream>>>(xn8, tern8, 1024, 4096,
      tile2e, rowmap, srow, he);
  k_gelu_rms<<<PADROWS,256,0,stream>>>(he, he8, qd, ptot);
  k_gemm8<false><<<dim3(8,PADTILES),256,0,stream>>>(he8, tern8 + (size_t)8*MATSZ, 4096, 1024,
      tile2e, nullptr, qd, y);
  k_combine<<<TOK,256,0,stream>>>(xattn, y, tokrow, w1b, out);
}

// Round 10
// 431.525 us; speedup vs baseline: 1.2670x; 1.2670x over previous
//
#include <hip/hip_runtime.h>
#include <math.h>

#define TOK 4096
#define DM 1024
#define DFF 4096
#define MATSZ 4194304   // 4096*1024 elements per expert matrix
#define PADROWS 9216
#define PADTILES 72

typedef unsigned short u16;
typedef unsigned int   u32;
typedef __attribute__((ext_vector_type(8))) __bf16 bf16x8;
typedef __attribute__((ext_vector_type(4))) float  f32x4;
typedef __attribute__((ext_vector_type(4))) int    i32x4;
typedef __attribute__((ext_vector_type(4))) float  f4v;

#define GLD16(gp, lp) __builtin_amdgcn_global_load_lds( \
    (const __attribute__((address_space(1))) void*)(gp), \
    (__attribute__((address_space(3))) void*)(lp), 16, 0, 0)

// ---------------- helpers ----------------
__device__ __forceinline__ float b2f(u16 u){ return __uint_as_float(((u32)u)<<16); }
__device__ __forceinline__ u16 f2b(float f){
  u32 i = __float_as_uint(f);
  u32 r = i + 0x7fffu + ((i>>16)&1u);
  return (u16)(r>>16);
}
__device__ __forceinline__ void unpack8(uint4 rw, float* dst){
  u32 u0=rw.x,u1=rw.y,u2=rw.z,u3=rw.w;
  dst[0]=__uint_as_float(u0<<16); dst[1]=__uint_as_float(u0&0xffff0000u);
  dst[2]=__uint_as_float(u1<<16); dst[3]=__uint_as_float(u1&0xffff0000u);
  dst[4]=__uint_as_float(u2<<16); dst[5]=__uint_as_float(u2&0xffff0000u);
  dst[6]=__uint_as_float(u3<<16); dst[7]=__uint_as_float(u3&0xffff0000u);
}
__device__ __forceinline__ float block_reduce_sum256(float v, float* red){
  #pragma unroll
  for (int off=32; off>0; off>>=1) v += __shfl_down(v, off);
  __syncthreads();
  if ((threadIdx.x & 63)==0) red[threadIdx.x>>6] = v;
  __syncthreads();
  return red[0]+red[1]+red[2]+red[3];
}
__device__ __forceinline__ float block_reduce_max256(float v, float* red){
  #pragma unroll
  for (int off=32; off>0; off>>=1) v = fmaxf(v, __shfl_down(v, off));
  __syncthreads();
  if ((threadIdx.x & 63)==0) red[threadIdx.x>>6] = v;
  __syncthreads();
  return fmaxf(fmaxf(red[0],red[1]), fmaxf(red[2],red[3]));
}

// ---------------- ternarize (alpha = mean|w| per expert matrix) ----------------
__global__ __launch_bounds__(256) void k_absum1(const float* __restrict__ up, const float* __restrict__ dn,
                                                float* __restrict__ partials){
  const int b = blockIdx.x;                 // 8192 blocks; 512 per matrix
  const size_t f4i = (size_t)b*2048;
  const f4v* s4 = (b < 4096) ? ((const f4v*)up + f4i) : ((const f4v*)dn + (f4i - 8388608));
  const int tid = threadIdx.x;
  float a0=0.f,a1=0.f,a2=0.f,a3=0.f;
  #pragma unroll
  for (int i=0;i<2;i++){
    f4v v0 = __builtin_nontemporal_load(s4 + i*1024 + tid);
    f4v v1 = __builtin_nontemporal_load(s4 + i*1024 + tid + 256);
    f4v v2 = __builtin_nontemporal_load(s4 + i*1024 + tid + 512);
    f4v v3 = __builtin_nontemporal_load(s4 + i*1024 + tid + 768);
    a0 += fabsf(v0[0])+fabsf(v0[1])+fabsf(v0[2])+fabsf(v0[3]);
    a1 += fabsf(v1[0])+fabsf(v1[1])+fabsf(v1[2])+fabsf(v1[3]);
    a2 += fabsf(v2[0])+fabsf(v2[1])+fabsf(v2[2])+fabsf(v2[3]);
    a3 += fabsf(v3[0])+fabsf(v3[1])+fabsf(v3[2])+fabsf(v3[3]);
  }
  __shared__ float red[4];
  float tot = block_reduce_sum256((a0+a1)+(a2+a3), red);
  if (tid==0) partials[b]=tot;
}
__global__ void k_absum2(const float* __restrict__ partials, float* __restrict__ thr){
  const int t=threadIdx.x;            // 256 threads: 16 per matrix
  const int m=t>>4, k=t&15;
  float s=0.f;
  for (int i=0;i<32;i++) s += partials[m*512 + k + i*16];
  s += __shfl_xor(s,1); s += __shfl_xor(s,2); s += __shfl_xor(s,4); s += __shfl_xor(s,8);
  if (k==0) thr[m]=0.5f*s/4194304.0f;
}
__global__ __launch_bounds__(256) void k_ternarize(const float* __restrict__ up, const float* __restrict__ dn,
                                                   const float* __restrict__ thr, signed char* __restrict__ tern){
  const int nvec = 16777216; // 67.1M / 4
  for (int i0 = blockIdx.x*1024 + threadIdx.x; i0 < nvec; i0 += gridDim.x*1024){
    const int i1 = i0 + 256, i2 = i0 + 512, i3 = i0 + 768;
    f4v w0 = (i0 < 8388608) ? __builtin_nontemporal_load((const f4v*)up + i0) : __builtin_nontemporal_load((const f4v*)dn + (i0-8388608));
    f4v w1 = (i1 < 8388608) ? __builtin_nontemporal_load((const f4v*)up + i1) : __builtin_nontemporal_load((const f4v*)dn + (i1-8388608));
    f4v w2 = (i2 < 8388608) ? __builtin_nontemporal_load((const f4v*)up + i2) : __builtin_nontemporal_load((const f4v*)dn + (i2-8388608));
    f4v w3 = (i3 < 8388608) ? __builtin_nontemporal_load((const f4v*)up + i3) : __builtin_nontemporal_load((const f4v*)dn + (i3-8388608));
    float t0 = thr[(int)(((size_t)i0*4)>>22)];
    float t1 = thr[(int)(((size_t)i1*4)>>22)];
    float t2 = thr[(int)(((size_t)i2*4)>>22)];
    float t3 = thr[(int)(((size_t)i3*4)>>22)];
    char4 c0, c1, c2, c3;
    c0.x=(fabsf(w0[0])>t0)?(w0[0]>0.f?1:-1):0; c0.y=(fabsf(w0[1])>t0)?(w0[1]>0.f?1:-1):0;
    c0.z=(fabsf(w0[2])>t0)?(w0[2]>0.f?1:-1):0; c0.w=(fabsf(w0[3])>t0)?(w0[3]>0.f?1:-1):0;
    c1.x=(fabsf(w1[0])>t1)?(w1[0]>0.f?1:-1):0; c1.y=(fabsf(w1[1])>t1)?(w1[1]>0.f?1:-1):0;
    c1.z=(fabsf(w1[2])>t1)?(w1[2]>0.f?1:-1):0; c1.w=(fabsf(w1[3])>t1)?(w1[3]>0.f?1:-1):0;
    c2.x=(fabsf(w2[0])>t2)?(w2[0]>0.f?1:-1):0; c2.y=(fabsf(w2[1])>t2)?(w2[1]>0.f?1:-1):0;
    c2.z=(fabsf(w2[2])>t2)?(w2[2]>0.f?1:-1):0; c2.w=(fabsf(w2[3])>t2)?(w2[3]>0.f?1:-1):0;
    c3.x=(fabsf(w3[0])>t3)?(w3[0]>0.f?1:-1):0; c3.y=(fabsf(w3[1])>t3)?(w3[1]>0.f?1:-1):0;
    c3.z=(fabsf(w3[2])>t3)?(w3[2]>0.f?1:-1):0; c3.w=(fabsf(w3[3])>t3)?(w3[3]>0.f?1:-1):0;
    *(char4*)(tern+(size_t)i0*4) = c0;
    *(char4*)(tern+(size_t)i1*4) = c1;
    *(char4*)(tern+(size_t)i2*4) = c2;
    *(char4*)(tern+(size_t)i3*4) = c3;
  }
}
__global__ __launch_bounds__(256) void k_f2b(const float* __restrict__ s, u16* __restrict__ d, int n4){
  int i = blockIdx.x*256+threadIdx.x;
  if (i<n4){
    float4 v=((const float4*)s)[i];
    ushort4 o; o.x=f2b(v.x); o.y=f2b(v.y); o.z=f2b(v.z); o.w=f2b(v.w);
    ((ushort4*)d)[i]=o;
  }
}

// ---------------- layernorm 1 ----------------
__global__ __launch_bounds__(256) void k_ln1(const float* __restrict__ x, const float* __restrict__ g,
                                             const float* __restrict__ b, u16* __restrict__ h){
  __shared__ float red[4];
  const int t=blockIdx.x, tid=threadIdx.x;
  float4 xv = ((const float4*)(x + (size_t)t*DM))[tid];
  float s  = xv.x+xv.y+xv.z+xv.w;
  float sq = xv.x*xv.x+xv.y*xv.y+xv.z*xv.z+xv.w*xv.w;
  float sum  = block_reduce_sum256(s, red);
  float sums = block_reduce_sum256(sq, red);
  float mu = sum*(1.0f/DM);
  float var = sums*(1.0f/DM) - mu*mu;
  float rstd = rsqrtf(var+1e-5f);
  float4 gv = ((const float4*)g)[tid];
  float4 bv = ((const float4*)b)[tid];
  ushort4 pk;
  pk.x = f2b((xv.x-mu)*rstd*gv.x+bv.x);
  pk.y = f2b((xv.y-mu)*rstd*gv.y+bv.y);
  pk.z = f2b((xv.z-mu)*rstd*gv.z+bv.z);
  pk.w = f2b((xv.w-mu)*rstd*gv.w+bv.w);
  ((ushort4*)(h + (size_t)t*DM))[tid] = pk;
}

// ---------------- bf16 MFMA GEMM: 128x128, BK=32, depth-2 prefetch (3 buffers, counted vmcnt) ----------------
template<int MODE>
__global__ __launch_bounds__(256) void k_gemm(const u16* __restrict__ A, const u16* __restrict__ B,
                                              int K, int ldc, const float* __restrict__ bias,
                                              const float* __restrict__ resid, void* __restrict__ Cout,
                                              u16* __restrict__ vT){
  __shared__ u16 As[3][128*32];
  __shared__ u16 Bs[3][128*32];
  const int tid = threadIdx.x;
  const int w = tid>>6, lane = tid&63;
  const int m0 = blockIdx.y*128, n0 = blockIdx.x*128;

  const int sr = lane>>2, ss = lane&3;
  const int ra0 = w*32 + sr, ra1 = ra0 + 16;
  const int kb0 = (ss ^ ((ra0>>1)&3))<<3;
  const int kb1 = (ss ^ ((ra1>>1)&3))<<3;
  const u16* pa0 = A + (size_t)(m0+ra0)*K + kb0;
  const u16* pa1 = A + (size_t)(m0+ra1)*K + kb1;
  const u16* pb0 = B + (size_t)(n0+ra0)*K + kb0;
  const u16* pb1 = B + (size_t)(n0+ra1)*K + kb1;
  const int lo0 = (w*32)*32, lo1 = lo0 + 16*32;

  const int wm = w>>1, wn = w&1;
  const int lr = lane&15, sl = lane>>4;
  int offA[4], offB[4];
  #pragma unroll
  for (int m=0;m<4;m++){ int r = wm*64 + m*16 + lr; offA[m] = r*64 + ((sl ^ ((r>>1)&3))<<4); }
  #pragma unroll
  for (int n=0;n<4;n++){ int r = wn*64 + n*16 + lr; offB[n] = r*64 + ((sl ^ ((r>>1)&3))<<4); }

  f32x4 acc[4][4] = {};
  const int NT = K>>5;
  GLD16(pa0, &As[0][lo0]); GLD16(pa1, &As[0][lo1]);
  GLD16(pb0, &Bs[0][lo0]); GLD16(pb1, &Bs[0][lo1]);
  pa0+=32; pa1+=32; pb0+=32; pb1+=32;
  GLD16(pa0, &As[1][lo0]); GLD16(pa1, &As[1][lo1]);
  GLD16(pb0, &Bs[1][lo0]); GLD16(pb1, &Bs[1][lo1]);
  pa0+=32; pa1+=32; pb0+=32; pb1+=32;

  int cur=0, nx2=2;
  for (int t=0;t<NT;t++){
    if (t+1<NT) asm volatile("s_waitcnt vmcnt(4) lgkmcnt(0)" ::: "memory");
    else        asm volatile("s_waitcnt vmcnt(0) lgkmcnt(0)" ::: "memory");
    __builtin_amdgcn_s_barrier();
    if (t+2<NT){
      GLD16(pa0, &As[nx2][lo0]); GLD16(pa1, &As[nx2][lo1]);
      GLD16(pb0, &Bs[nx2][lo0]); GLD16(pb1, &Bs[nx2][lo1]);
      pa0+=32; pa1+=32; pb0+=32; pb1+=32;
    }
    const char* Ab = (const char*)As[cur];
    const char* Bb = (const char*)Bs[cur];
    bf16x8 af[4], bfv[4];
    #pragma unroll
    for (int m=0;m<4;m++) af[m] = *(const bf16x8*)(Ab + offA[m]);
    #pragma unroll
    for (int n=0;n<4;n++) bfv[n] = *(const bf16x8*)(Bb + offB[n]);
    #pragma unroll
    for (int m=0;m<4;m++)
      #pragma unroll
      for (int n=0;n<4;n++)
        acc[m][n] = __builtin_amdgcn_mfma_f32_16x16x32_bf16(af[m], bfv[n], acc[m][n], 0, 0, 0);
    cur = (cur==2)?0:cur+1;
    nx2 = (nx2==2)?0:nx2+1;
  }

  const int rowg = lane>>4;
  #pragma unroll
  for (int m=0;m<4;m++){
    const int rbase = m0 + wm*64 + m*16 + rowg*4;
    #pragma unroll
    for (int n=0;n<4;n++){
      const int col = n0 + wn*64 + n*16 + lr;
      if (MODE==2){
        u16 pk4[4];
        #pragma unroll
        for (int j=0;j<4;j++){
          float v = acc[m][n][j] + bias[col];
          pk4[j] = f2b(v);
          ((u16*)Cout)[(size_t)(rbase+j)*ldc + col] = pk4[j];
        }
        if (col >= 2048){
          const int d = col-2048, hd = d>>6, dd = d&63;
          const int bb = rbase>>10, s = rbase&1023;
          uint2 pk; pk.x = (u32)pk4[0] | ((u32)pk4[1]<<16); pk.y = (u32)pk4[2] | ((u32)pk4[3]<<16);
          *(uint2*)(vT + (((size_t)((bb*16+hd)*64+dd))<<10) + s) = pk;
        }
      } else {
        #pragma unroll
        for (int j=0;j<4;j++){
          const size_t ci = (size_t)(rbase+j)*ldc + col;
          ((float*)Cout)[ci] = acc[m][n][j] + bias[col] + resid[ci];
        }
      }
    }
  }
}

// ---------------- i8 MFMA GEMM for MoE, depth-2 prefetch (3 buffers, counted vmcnt) ----------------
template<bool GATHER>
__global__ __launch_bounds__(256) void k_gemm8(const signed char* __restrict__ A, const signed char* __restrict__ Ball,
                                               int K, int ldc,
                                               const int* __restrict__ tile2e, const int* __restrict__ rowmap,
                                               const float* __restrict__ rscale, u16* __restrict__ Cout){
  int e = tile2e[blockIdx.y];
  if (e < 0) return;
  const signed char* Bp = Ball + (size_t)e * MATSZ;
  __shared__ signed char As[3][128*64];
  __shared__ signed char Bs[3][128*64];
  const int tid = threadIdx.x;
  const int w = tid>>6, lane = tid&63;
  const int m0 = blockIdx.y*128, n0 = blockIdx.x*128;

  const int sr = lane>>2, ss = lane&3;
  const int ra0 = w*32 + sr, ra1 = ra0 + 16;
  const int kb0 = (ss ^ ((ra0>>1)&3))<<4;
  const int kb1 = (ss ^ ((ra1>>1)&3))<<4;
  const signed char *pa0, *pa1;
  if (GATHER){
    int t0 = rowmap[m0+ra0]; if (t0<0) t0 = 0;
    int t1 = rowmap[m0+ra1]; if (t1<0) t1 = 0;
    pa0 = A + (size_t)t0*K + kb0;
    pa1 = A + (size_t)t1*K + kb1;
  } else {
    pa0 = A + (size_t)(m0+ra0)*K + kb0;
    pa1 = A + (size_t)(m0+ra1)*K + kb1;
  }
  const signed char* pb0 = Bp + (size_t)(n0+ra0)*K + kb0;
  const signed char* pb1 = Bp + (size_t)(n0+ra1)*K + kb1;
  const int lo0 = (w*32)*64, lo1 = lo0 + 16*64;

  const int wm = w>>1, wn = w&1;
  const int lr = lane&15, sl = lane>>4;
  int offA[4], offB[4];
  #pragma unroll
  for (int m=0;m<4;m++){ int r = wm*64 + m*16 + lr; offA[m] = r*64 + ((sl ^ ((r>>1)&3))<<4); }
  #pragma unroll
  for (int n=0;n<4;n++){ int r = wn*64 + n*16 + lr; offB[n] = r*64 + ((sl ^ ((r>>1)&3))<<4); }

  i32x4 acc[4][4] = {};
  const int NT = K>>6;
  GLD16(pa0, &As[0][lo0]); GLD16(pa1, &As[0][lo1]);
  GLD16(pb0, &Bs[0][lo0]); GLD16(pb1, &Bs[0][lo1]);
  pa0+=64; pa1+=64; pb0+=64; pb1+=64;
  GLD16(pa0, &As[1][lo0]); GLD16(pa1, &As[1][lo1]);
  GLD16(pb0, &Bs[1][lo0]); GLD16(pb1, &Bs[1][lo1]);
  pa0+=64; pa1+=64; pb0+=64; pb1+=64;

  int cur=0, nx2=2;
  for (int t=0;t<NT;t++){
    if (t+1<NT) asm volatile("s_waitcnt vmcnt(4) lgkmcnt(0)" ::: "memory");
    else        asm volatile("s_waitcnt vmcnt(0) lgkmcnt(0)" ::: "memory");
    __builtin_amdgcn_s_barrier();
    if (t+2<NT){
      GLD16(pa0, &As[nx2][lo0]); GLD16(pa1, &As[nx2][lo1]);
      GLD16(pb0, &Bs[nx2][lo0]); GLD16(pb1, &Bs[nx2][lo1]);
      pa0+=64; pa1+=64; pb0+=64; pb1+=64;
    }
    const char* Ab = (const char*)As[cur];
    const char* Bb = (const char*)Bs[cur];
    i32x4 af[4], bfv[4];
    #pragma unroll
    for (int m=0;m<4;m++) af[m] = *(const i32x4*)(Ab + offA[m]);
    #pragma unroll
    for (int n=0;n<4;n++) bfv[n] = *(const i32x4*)(Bb + offB[n]);
    #pragma unroll
    for (int m=0;m<4;m++)
      #pragma unroll
      for (int n=0;n<4;n++)
        acc[m][n] = __builtin_amdgcn_mfma_i32_16x16x64_i8(af[m], bfv[n], acc[m][n], 0, 0, 0);
    cur = (cur==2)?0:cur+1;
    nx2 = (nx2==2)?0:nx2+1;
  }

  const int rowg = lane>>4;
  #pragma unroll
  for (int m=0;m<4;m++){
    const int rbase = m0 + wm*64 + m*16 + rowg*4;
    #pragma unroll
    for (int n=0;n<4;n++){
      const int col = n0 + wn*64 + n*16 + lr;
      #pragma unroll
      for (int j=0;j<4;j++){
        float v = (float)acc[m][n][j] * rscale[rbase+j];
        Cout[(size_t)(rbase+j)*ldc + col] = f2b(v);
      }
    }
  }
}

// ---------------- MFMA flash attention (exp2 + defer-max + dbuf KV + setprio) ----------------
__global__ __launch_bounds__(256) void k_attn_mfma(const u16* __restrict__ qkv, const u16* __restrict__ vT,
                                                   u16* __restrict__ ob){
  __shared__ u16 Ks[2][64*64];
  __shared__ u16 Vs[2][64*64];
  __shared__ u16 Pa[4*16*64];
  const int qt=blockIdx.x, hh=blockIdx.y, bb=blockIdx.z;
  const int tid=threadIdx.x, w=tid>>6, lane=tid&63;
  const int g=lane>>4, lr=lane&15;
  const int srow8=lane>>3, sslot=lane&7;
  const float RTHR = 11.5f;   // log2 units

  bf16x8 qa[2];
  {
    const u16* qp = qkv + ((size_t)(bb*1024 + qt*64 + w*16 + lr))*3072 + hh*64 + g*8;
    #pragma unroll
    for (int c=0;c<2;c++){
      uint4 raw = *(const uint4*)(qp + c*32);
      float tv[8]; unpack8(raw,tv);
      union { u16 s[8]; bf16x8 v; } qq;
      #pragma unroll
      for (int i=0;i<8;i++) qq.s[i] = f2b(tv[i]*0.18033688f);
      qa[c] = qq.v;
    }
  }

  float mrow[4], lrow[4];
  #pragma unroll
  for (int j=0;j<4;j++){ mrow[j]=-1e30f; lrow[j]=0.f; }
  f32x4 acc_o[4] = {};

  char* pbuf = (char*)Pa + (w<<11);

  const int row0 = w*16 + srow8, row1 = row0 + 8;
  const int fs0 = (sslot ^ (row0&7))<<3;
  const int fs1 = (sslot ^ (row1&7))<<3;
  const int ldso0 = (w*16)*64, ldso1 = (w*16+8)*64;

  {
    const u16* gk0 = qkv + ((size_t)(bb*1024 + row0))*3072 + 1024 + hh*64 + fs0;
    const u16* gk1 = qkv + ((size_t)(bb*1024 + row1))*3072 + 1024 + hh*64 + fs1;
    GLD16(gk0, &Ks[0][ldso0]); GLD16(gk1, &Ks[0][ldso1]);
    const u16* gv0 = vT + ((size_t)((bb*16+hh)*64 + row0))*1024 + fs0;
    const u16* gv1 = vT + ((size_t)((bb*16+hh)*64 + row1))*1024 + fs1;
    GLD16(gv0, &Vs[0][ldso0]); GLD16(gv1, &Vs[0][ldso1]);
  }
  __syncthreads();

  for (int kt=0; kt<16; ++kt){
    if (kt+1<16){
      const int nb=(kt+1)&1;
      const u16* gk0 = qkv + ((size_t)(bb*1024 + (kt+1)*64 + row0))*3072 + 1024 + hh*64 + fs0;
      const u16* gk1 = qkv + ((size_t)(bb*1024 + (kt+1)*64 + row1))*3072 + 1024 + hh*64 + fs1;
      GLD16(gk0, &Ks[nb][ldso0]); GLD16(gk1, &Ks[nb][ldso1]);
      const u16* gv0 = vT + ((size_t)((bb*16+hh)*64 + row0))*1024 + (kt+1)*64 + fs0;
      const u16* gv1 = vT + ((size_t)((bb*16+hh)*64 + row1))*1024 + (kt+1)*64 + fs1;
      GLD16(gv0, &Vs[nb][ldso0]); GLD16(gv1, &Vs[nb][ldso1]);
    }
    const char* Kb = (const char*)Ks[kt&1];
    const char* Vb = (const char*)Vs[kt&1];

    f32x4 sacc[4] = {};
    __builtin_amdgcn_s_setprio(1);
    #pragma unroll
    for (int ct=0; ct<4; ct++){
      const int kv = ct*16 + lr;
      const char* krow = Kb + kv*128;
      bf16x8 kb0 = *(const bf16x8*)(krow + (((g  ) ^ (kv&7))<<4));
      bf16x8 kb1 = *(const bf16x8*)(krow + (((4+g) ^ (kv&7))<<4));
      sacc[ct] = __builtin_amdgcn_mfma_f32_16x16x32_bf16(qa[0], kb0, sacc[ct], 0,0,0);
      sacc[ct] = __builtin_amdgcn_mfma_f32_16x16x32_bf16(qa[1], kb1, sacc[ct], 0,0,0);
    }
    __builtin_amdgcn_s_setprio(0);

    float vmx[4]; bool okl = true;
    #pragma unroll
    for (int j=0;j<4;j++){
      vmx[j] = fmaxf(fmaxf(sacc[0][j],sacc[1][j]), fmaxf(sacc[2][j],sacc[3][j]));
      okl = okl && (vmx[j]-mrow[j] <= RTHR);
    }
    float psum[4] = {0.f,0.f,0.f,0.f};
    if (__all((int)okl)){
      #pragma unroll
      for (int ct=0; ct<4; ct++){
        #pragma unroll
        for (int j=0;j<4;j++){
          float p = exp2f(sacc[ct][j]-mrow[j]);
          psum[j] += p;
          const int q = g*4+j, k = ct*16+lr;
          *(u16*)(pbuf + q*128 + (((k>>3) ^ (q&7))<<4) + ((k&7)<<1)) = f2b(p);
        }
      }
      #pragma unroll
      for (int j=0;j<4;j++){
        float s = psum[j];
        s += __shfl_xor(s,1); s += __shfl_xor(s,2); s += __shfl_xor(s,4); s += __shfl_xor(s,8);
        lrow[j] += s;
      }
    } else {
      float mnew[4], corr[4];
      #pragma unroll
      for (int j=0;j<4;j++){
        float v = vmx[j];
        v = fmaxf(v, __shfl_xor(v,1));
        v = fmaxf(v, __shfl_xor(v,2));
        v = fmaxf(v, __shfl_xor(v,4));
        v = fmaxf(v, __shfl_xor(v,8));
        mnew[j] = fmaxf(mrow[j], v);
        corr[j] = exp2f(mrow[j]-mnew[j]);
        mrow[j] = mnew[j];
      }
      #pragma unroll
      for (int ct=0; ct<4; ct++){
        #pragma unroll
        for (int j=0;j<4;j++){
          float p = exp2f(sacc[ct][j]-mrow[j]);
          psum[j] += p;
          const int q = g*4+j, k = ct*16+lr;
          *(u16*)(pbuf + q*128 + (((k>>3) ^ (q&7))<<4) + ((k&7)<<1)) = f2b(p);
        }
      }
      #pragma unroll
      for (int j=0;j<4;j++){
        float s = psum[j];
        s += __shfl_xor(s,1); s += __shfl_xor(s,2); s += __shfl_xor(s,4); s += __shfl_xor(s,8);
        lrow[j] = lrow[j]*corr[j] + s;
      }
      #pragma unroll
      for (int ctd=0; ctd<4; ctd++)
        #pragma unroll
        for (int j=0;j<4;j++) acc_o[ctd][j] *= corr[j];
    }

    __builtin_amdgcn_s_setprio(1);
    #pragma unroll
    for (int c=0;c<2;c++){
      bf16x8 pa = *(const bf16x8*)(pbuf + lr*128 + (((c*4+g) ^ (lr&7))<<4));
      #pragma unroll
      for (int ctd=0; ctd<4; ctd++){
        const int d = ctd*16 + lr;
        bf16x8 vb = *(const bf16x8*)(Vb + d*128 + (((c*4+g) ^ (d&7))<<4));
        acc_o[ctd] = __builtin_amdgcn_mfma_f32_16x16x32_bf16(pa, vb, acc_o[ctd], 0,0,0);
      }
    }
    __builtin_amdgcn_s_setprio(0);
    __syncthreads();
  }

  #pragma unroll
  for (int j=0;j<4;j++){
    const float inv = 1.0f/lrow[j];
    const int row = bb*1024 + qt*64 + w*16 + g*4 + j;
    u16* op = ob + (size_t)row*DM + hh*64 + lr;
    #pragma unroll
    for (int ctd=0; ctd<4; ctd++) op[ctd*16] = f2b(acc_o[ctd][j]*inv);
  }
}

// ---------------- layernorm 2 + geometric router + i8 activation quant ----------------
__global__ __launch_bounds__(256) void k_ln2_router(const float* __restrict__ xa, const float* __restrict__ g,
                                                    const float* __restrict__ b, const float* __restrict__ rw,
                                                    signed char* __restrict__ xn8, int* __restrict__ eidx,
                                                    float* __restrict__ w1o, float* __restrict__ sbc){
  __shared__ float red[4];
  const int t=blockIdx.x, tid=threadIdx.x;
  float4 xv = ((const float4*)(xa + (size_t)t*DM))[tid];
  float s  = xv.x+xv.y+xv.z+xv.w;
  float sq = xv.x*xv.x+xv.y*xv.y+xv.z*xv.z+xv.w*xv.w;
  float sum  = block_reduce_sum256(s, red);
  float sums = block_reduce_sum256(sq, red);
  float mu = sum*(1.0f/DM);
  float var = sums*(1.0f/DM) - mu*mu;
  float rstd = rsqrtf(var+1e-5f);
  float4 gv = ((const float4*)g)[tid];
  float4 bv = ((const float4*)b)[tid];
  float y0=(xv.x-mu)*rstd*gv.x+bv.x;
  float y1=(xv.y-mu)*rstd*gv.y+bv.y;
  float y2=(xv.z-mu)*rstd*gv.z+bv.z;
  float y3=(xv.w-mu)*rstd*gv.w+bv.w;
  float4 r0=((const float4*)(rw+0*DM))[tid];
  float4 r1=((const float4*)(rw+1*DM))[tid];
  float4 r2=((const float4*)(rw+2*DM))[tid];
  float4 r3=((const float4*)(rw+3*DM))[tid];
  float nsq = y0*y0+y1*y1+y2*y2+y3*y3;
  float d0 = y0*r0.x+y1*r0.y+y2*r0.z+y3*r0.w;
  float d1 = y0*r1.x+y1*r1.y+y2*r1.z+y3*r1.w;
  float d2 = y0*r2.x+y1*r2.y+y2*r2.z+y3*r2.w;
  float d3 = y0*r3.x+y1*r3.y+y2*r3.z+y3*r3.w;
  float am = fmaxf(fmaxf(fabsf(y0),fabsf(y1)), fmaxf(fabsf(y2),fabsf(y3)));
  float AM = block_reduce_max256(am, red);
  float SQ = block_reduce_sum256(nsq, red);
  float D0 = block_reduce_sum256(d0, red);
  float D1 = block_reduce_sum256(d1, red);
  float D2 = block_reduce_sum256(d2, red);
  float D3 = block_reduce_sum256(d3, red);
  float qs = fmaxf(AM, 1e-12f) * (1.0f/127.0f);
  float inv = 1.0f/qs;
  char4 c;
  c.x = (signed char)__float2int_rn(y0*inv);
  c.y = (signed char)__float2int_rn(y1*inv);
  c.z = (signed char)__float2int_rn(y2*inv);
  c.w = (signed char)__float2int_rn(y3*inv);
  ((char4*)(xn8 + (size_t)t*DM))[tid] = c;
  if (tid==0){
    float n = fmaxf(sqrtf(D0*D0+D1*D1+D2*D2+D3*D3), 1e-12f);
    float h0=D0/n, h1=D1/n, h2=D2/n, h3=D3/n;
    float dot0 = 0.70710678f*(h0-h1);
    float dot1 = 0.70710678f*(h1-h2);
    float dot2 = h2;
    float dot3 = (-0.5f*h0+0.5f*h1+0.5f*h2+0.80901699f*h3)*0.8437966f;
    int ch = (int)(dot0>=0.f) + 2*(int)(dot1>=0.f) + 4*(int)(dot2>=0.f) + 8*(int)(dot3>=0.f);
    int e1 = ch & 7;
    int e2 = ((ch>>1)+1) & 7;
    if (e1==e2) e2=(e2+1)&7;
    float conf = fminf(fminf(fabsf(dot0),fabsf(dot1)), fminf(fabsf(dot2),fabsf(dot3)));
    eidx[2*t]=e1; eidx[2*t+1]=e2;
    w1o[t]=0.5f + 0.3f/(1.0f+__expf(-conf));
    sbc[t]= qs / (sqrtf(SQ*(1.0f/DM))+1e-8f);
  }
}

// ---------------- routing: histogram + offsets + scatter in ONE single-block kernel ----------------
// All binning via LDS atomics (8 cells) — no global same-line atomic serialization.
__global__ __launch_bounds__(256) void k_route(const int* __restrict__ eidx, const float* __restrict__ sbc,
                                               int* __restrict__ tile2e, int* __restrict__ rowmap,
                                               float* __restrict__ srow, int* __restrict__ tokrow,
                                               int* __restrict__ ptot){
  __shared__ int cnt[8], pos[8];
  const int tid = threadIdx.x;
  if (tid<8) cnt[tid]=0;
  __syncthreads();
  for (int t=tid; t<TOK; t+=256){
    atomicAdd(&cnt[eidx[2*t]],1);
    atomicAdd(&cnt[eidx[2*t+1]],1);
  }
  __syncthreads();
  if (tid==0){
    int off=0;
    for (int e=0;e<8;e++){
      pos[e]=off;
      int pad = ((cnt[e]+127)>>7)<<7;
      int t0=off>>7, t1=(off+pad)>>7;
      for (int tt=t0;tt<t1;tt++) tile2e[tt]=e;
      off+=pad;
    }
    *ptot=off;
    for (int tt=off>>7; tt<PADTILES; tt++) tile2e[tt]=-1;
  }
  __syncthreads();
  for (int i=tid;i<PADROWS;i+=256){ rowmap[i]=-1; srow[i]=0.f; }
  __syncthreads();
  for (int t=tid; t<TOK; t+=256){
    int e1=eidx[2*t], e2=eidx[2*t+1];
    float s=sbc[t];
    int r1 = atomicAdd(&pos[e1],1);
    rowmap[r1]=t; srow[r1]=s; tokrow[2*t]=r1;
    int r2 = atomicAdd(&pos[e2],1);
    rowmap[r2]=t; srow[r2]=s; tokrow[2*t+1]=r2;
  }
}

// ---------------- GELU (exact) + per-row RMS normalize + i8 quant ----------------
__global__ __launch_bounds__(256) void k_gelu_rms(const u16* __restrict__ he, signed char* __restrict__ he8,
                                                  float* __restrict__ qd, const int* __restrict__ ptot){
  const int row = blockIdx.x;
  if (row >= *ptot) return;
  const u16* p = he + (size_t)row*DFF;
  const int tid=threadIdx.x;
  uint4 rw0 = ((const uint4*)p)[2*tid];
  uint4 rw1 = ((const uint4*)p)[2*tid+1];
  float v[16];
  unpack8(rw0, v); unpack8(rw1, v+8);
  float sq=0.f;
  #pragma unroll
  for (int q=0;q<16;q++){
    float xg = v[q];
    float ge = 0.5f*xg*(1.0f+erff(xg*0.70710678f));
    v[q]=ge; sq += ge*ge;
  }
  __shared__ float red[4];
  float SQ = block_reduce_sum256(sq, red);
  float s = 1.0f/(sqrtf(SQ*(1.0f/DFF))+1e-8f);
  float am = 0.f;
  #pragma unroll
  for (int q=0;q<16;q++){ v[q]*=s; am = fmaxf(am, fabsf(v[q])); }
  float AM = block_reduce_max256(am, red);
  float q8 = fmaxf(AM, 1e-12f) * (1.0f/127.0f);
  float inv = 1.0f/q8;
  union { signed char c[16]; uint4 u; } pk;
  #pragma unroll
  for (int q=0;q<16;q++) pk.c[q] = (signed char)__float2int_rn(v[q]*inv);
  ((uint4*)(he8 + (size_t)row*DFF))[tid] = pk.u;
  if (tid==0) qd[row] = q8;
}

// ---------------- combine ----------------
__global__ __launch_bounds__(256) void k_combine(const float* __restrict__ xa, const u16* __restrict__ y,
                                                 const int* __restrict__ tokrow, const float* __restrict__ w1,
                                                 float* __restrict__ out){
  const int t=blockIdx.x, tid=threadIdx.x;
  const int r1=tokrow[2*t], r2=tokrow[2*t+1];
  const float a = w1[t], bw = 1.0f-a;
  float4 xv = ((const float4*)(xa + (size_t)t*DM))[tid];
  ushort4 y1 = ((const ushort4*)(y + (size_t)r1*DM))[tid];
  ushort4 y2 = ((const ushort4*)(y + (size_t)r2*DM))[tid];
  float4 o;
  o.x = xv.x + a*b2f(y1.x) + bw*b2f(y2.x);
  o.y = xv.y + a*b2f(y1.y) + bw*b2f(y2.y);
  o.z = xv.z + a*b2f(y1.z) + bw*b2f(y2.z);
  o.w = xv.w + a*b2f(y1.w) + bw*b2f(y2.w);
  ((float4*)(out + (size_t)t*DM))[tid] = o;
}

extern "C" void kernel_launch(void* const* d_in, const int* in_sizes, int n_in,
                              void* d_out, int out_size, void* d_ws, size_t ws_size,
                              hipStream_t stream){
  (void)in_sizes; (void)n_in; (void)out_size; (void)ws_size;
  const float* x    = (const float*)d_in[0];
  const float* g1   = (const float*)d_in[1];
  const float* b1   = (const float*)d_in[2];
  const float* g2   = (const float*)d_in[3];
  const float* b2   = (const float*)d_in[4];
  const float* in_w = (const float*)d_in[5];
  const float* in_b = (const float*)d_in[6];
  const float* out_w= (const float*)d_in[7];
  const float* out_b= (const float*)d_in[8];
  const float* rw   = (const float*)d_in[9];
  const float* up_w = (const float*)d_in[10];
  const float* dn_w = (const float*)d_in[11];
  float* out = (float*)d_out;

  char* base = (char*)d_ws; size_t off=0;
  auto alloc = [&](size_t bytes)->char*{ char* p = base+off; off=(off+bytes+255)&~(size_t)255; return p; };
  u16* h      = (u16*)alloc((size_t)TOK*DM*2);
  u16* qkv    = (u16*)alloc((size_t)TOK*3072*2);
  u16* ob     = (u16*)alloc((size_t)TOK*DM*2);
  float* xattn= (float*)alloc((size_t)TOK*DM*4);
  signed char* xn8 = (signed char*)alloc((size_t)TOK*DM);
  signed char* tern8 = (signed char*)alloc((size_t)16*MATSZ);
  u16* wbf_in = (u16*)alloc((size_t)3145728*2);
  u16* wbf_out= (u16*)alloc((size_t)1048576*2);
  u16* vT     = (u16*)alloc((size_t)4*16*64*1024*2);
  u16* he     = (u16*)alloc((size_t)PADROWS*DFF*2);
  signed char* he8 = (signed char*)alloc((size_t)PADROWS*DFF);
  u16* y      = (u16*)alloc((size_t)PADROWS*DM*2);
  float* partials = (float*)alloc(8192*4);
  float* thr  = (float*)alloc(64);
  int* offs   = (int*)alloc(64);
  int* ptot   = (int*)alloc(64);
  int* eidx   = (int*)alloc((size_t)TOK*2*4);
  float* w1b  = (float*)alloc((size_t)TOK*4);
  float* sbc  = (float*)alloc((size_t)TOK*4);
  float* srow = (float*)alloc((size_t)PADROWS*4);
  float* qd   = (float*)alloc((size_t)PADROWS*4);
  int* tokrow = (int*)alloc((size_t)TOK*2*4);
  int* rowmap = (int*)alloc((size_t)PADROWS*4);
  int* tile2e = (int*)alloc(PADTILES*4);
  (void)offs;

  k_absum1<<<8192,256,0,stream>>>(up_w, dn_w, partials);
  k_absum2<<<1,256,0,stream>>>(partials, thr);
  k_ternarize<<<8192,256,0,stream>>>(up_w, dn_w, thr, tern8);
  k_f2b<<<3072,256,0,stream>>>(in_w, wbf_in, 786432);
  k_f2b<<<1024,256,0,stream>>>(out_w, wbf_out, 262144);
  k_ln1<<<TOK,256,0,stream>>>(x, g1, b1, h);
  k_gemm<2><<<dim3(24,32),256,0,stream>>>(h, wbf_in, 1024, 3072, in_b, nullptr, qkv, vT);
  k_attn_mfma<<<dim3(16,16,4),256,0,stream>>>(qkv, vT, ob);
  k_gemm<3><<<dim3(8,32),256,0,stream>>>(ob, wbf_out, 1024, 1024, out_b, x, xattn, nullptr);
  k_ln2_router<<<TOK,256,0,stream>>>(xattn, g2, b2, rw, xn8, eidx, w1b, sbc);
  k_route<<<1,256,0,stream>>>(eidx, sbc, tile2e, rowmap, srow, tokrow, ptot);
  k_gemm8<true><<<dim3(32,PADTILES),256,0,stream>>>(xn8, tern8, 1024, 4096,
      tile2e, rowmap, srow, he);
  k_gelu_rms<<<PADROWS,256,0,stream>>>(he, he8, qd, ptot);
  k_gemm8<false><<<dim3(8,PADTILES),256,0,stream>>>(he8, tern8 + (size_t)8*MATSZ, 4096, 1024,
      tile2e, nullptr, qd, y);
  k_combine<<<TOK,256,0,stream>>>(xattn, y, tokrow, w1b, out);
}

// Round 11
// 423.250 us; speedup vs baseline: 1.2917x; 1.0195x over previous
//
#include <hip/hip_runtime.h>
#include <math.h>

#define TOK 4096
#define DM 1024
#define DFF 4096
#define MATSZ 4194304   // 4096*1024 elements per expert matrix
#define PADROWS 9216
#define PADTILES 72

typedef unsigned short u16;
typedef unsigned int   u32;
typedef __attribute__((ext_vector_type(8))) __bf16 bf16x8;
typedef __attribute__((ext_vector_type(4))) float  f32x4;
typedef __attribute__((ext_vector_type(4))) int    i32x4;
typedef __attribute__((ext_vector_type(4))) float  f4v;

#define GLD16(gp, lp) __builtin_amdgcn_global_load_lds( \
    (const __attribute__((address_space(1))) void*)(gp), \
    (__attribute__((address_space(3))) void*)(lp), 16, 0, 0)

// XCD-aware bijective block swizzle (nwg % 8 == 0): each XCD gets a contiguous chunk
__device__ __forceinline__ void xcd_swizzle(int &bx, int &by){
  const int gx = gridDim.x;
  const int nwg = gx * gridDim.y;
  int flat = blockIdx.y * gx + blockIdx.x;
  int wg = (flat & 7) * (nwg >> 3) + (flat >> 3);
  bx = wg % gx; by = wg / gx;
}

// ---------------- helpers ----------------
__device__ __forceinline__ float b2f(u16 u){ return __uint_as_float(((u32)u)<<16); }
__device__ __forceinline__ u16 f2b(float f){
  u32 i = __float_as_uint(f);
  u32 r = i + 0x7fffu + ((i>>16)&1u);
  return (u16)(r>>16);
}
__device__ __forceinline__ void unpack8(uint4 rw, float* dst){
  u32 u0=rw.x,u1=rw.y,u2=rw.z,u3=rw.w;
  dst[0]=__uint_as_float(u0<<16); dst[1]=__uint_as_float(u0&0xffff0000u);
  dst[2]=__uint_as_float(u1<<16); dst[3]=__uint_as_float(u1&0xffff0000u);
  dst[4]=__uint_as_float(u2<<16); dst[5]=__uint_as_float(u2&0xffff0000u);
  dst[6]=__uint_as_float(u3<<16); dst[7]=__uint_as_float(u3&0xffff0000u);
}
__device__ __forceinline__ float block_reduce_sum256(float v, float* red){
  #pragma unroll
  for (int off=32; off>0; off>>=1) v += __shfl_down(v, off);
  __syncthreads();
  if ((threadIdx.x & 63)==0) red[threadIdx.x>>6] = v;
  __syncthreads();
  return red[0]+red[1]+red[2]+red[3];
}
__device__ __forceinline__ float block_reduce_max256(float v, float* red){
  #pragma unroll
  for (int off=32; off>0; off>>=1) v = fmaxf(v, __shfl_down(v, off));
  __syncthreads();
  if ((threadIdx.x & 63)==0) red[threadIdx.x>>6] = v;
  __syncthreads();
  return fmaxf(fmaxf(red[0],red[1]), fmaxf(red[2],red[3]));
}

// ---------------- ternarize (alpha = mean|w| per expert matrix) ----------------
__global__ __launch_bounds__(256) void k_absum1(const float* __restrict__ up, const float* __restrict__ dn,
                                                float* __restrict__ partials){
  const int b = blockIdx.x;                 // 8192 blocks; 512 per matrix
  const size_t f4i = (size_t)b*2048;
  const f4v* s4 = (b < 4096) ? ((const f4v*)up + f4i) : ((const f4v*)dn + (f4i - 8388608));
  const int tid = threadIdx.x;
  float a0=0.f,a1=0.f,a2=0.f,a3=0.f;
  #pragma unroll
  for (int i=0;i<2;i++){
    f4v v0 = __builtin_nontemporal_load(s4 + i*1024 + tid);
    f4v v1 = __builtin_nontemporal_load(s4 + i*1024 + tid + 256);
    f4v v2 = __builtin_nontemporal_load(s4 + i*1024 + tid + 512);
    f4v v3 = __builtin_nontemporal_load(s4 + i*1024 + tid + 768);
    a0 += fabsf(v0[0])+fabsf(v0[1])+fabsf(v0[2])+fabsf(v0[3]);
    a1 += fabsf(v1[0])+fabsf(v1[1])+fabsf(v1[2])+fabsf(v1[3]);
    a2 += fabsf(v2[0])+fabsf(v2[1])+fabsf(v2[2])+fabsf(v2[3]);
    a3 += fabsf(v3[0])+fabsf(v3[1])+fabsf(v3[2])+fabsf(v3[3]);
  }
  __shared__ float red[4];
  float tot = block_reduce_sum256((a0+a1)+(a2+a3), red);
  if (tid==0) partials[b]=tot;
}
__global__ void k_absum2(const float* __restrict__ partials, float* __restrict__ thr){
  const int t=threadIdx.x;            // 256 threads: 16 per matrix
  const int m=t>>4, k=t&15;
  float s=0.f;
  for (int i=0;i<32;i++) s += partials[m*512 + k + i*16];
  s += __shfl_xor(s,1); s += __shfl_xor(s,2); s += __shfl_xor(s,4); s += __shfl_xor(s,8);
  if (k==0) thr[m]=0.5f*s/4194304.0f;
}
__global__ __launch_bounds__(256) void k_ternarize(const float* __restrict__ up, const float* __restrict__ dn,
                                                   const float* __restrict__ thr, signed char* __restrict__ tern){
  const int nvec = 16777216; // 67.1M / 4
  for (int i0 = blockIdx.x*1024 + threadIdx.x; i0 < nvec; i0 += gridDim.x*1024){
    const int i1 = i0 + 256, i2 = i0 + 512, i3 = i0 + 768;
    f4v w0 = (i0 < 8388608) ? __builtin_nontemporal_load((const f4v*)up + i0) : __builtin_nontemporal_load((const f4v*)dn + (i0-8388608));
    f4v w1 = (i1 < 8388608) ? __builtin_nontemporal_load((const f4v*)up + i1) : __builtin_nontemporal_load((const f4v*)dn + (i1-8388608));
    f4v w2 = (i2 < 8388608) ? __builtin_nontemporal_load((const f4v*)up + i2) : __builtin_nontemporal_load((const f4v*)dn + (i2-8388608));
    f4v w3 = (i3 < 8388608) ? __builtin_nontemporal_load((const f4v*)up + i3) : __builtin_nontemporal_load((const f4v*)dn + (i3-8388608));
    float t0 = thr[(int)(((size_t)i0*4)>>22)];
    float t1 = thr[(int)(((size_t)i1*4)>>22)];
    float t2 = thr[(int)(((size_t)i2*4)>>22)];
    float t3 = thr[(int)(((size_t)i3*4)>>22)];
    char4 c0, c1, c2, c3;
    c0.x=(fabsf(w0[0])>t0)?(w0[0]>0.f?1:-1):0; c0.y=(fabsf(w0[1])>t0)?(w0[1]>0.f?1:-1):0;
    c0.z=(fabsf(w0[2])>t0)?(w0[2]>0.f?1:-1):0; c0.w=(fabsf(w0[3])>t0)?(w0[3]>0.f?1:-1):0;
    c1.x=(fabsf(w1[0])>t1)?(w1[0]>0.f?1:-1):0; c1.y=(fabsf(w1[1])>t1)?(w1[1]>0.f?1:-1):0;
    c1.z=(fabsf(w1[2])>t1)?(w1[2]>0.f?1:-1):0; c1.w=(fabsf(w1[3])>t1)?(w1[3]>0.f?1:-1):0;
    c2.x=(fabsf(w2[0])>t2)?(w2[0]>0.f?1:-1):0; c2.y=(fabsf(w2[1])>t2)?(w2[1]>0.f?1:-1):0;
    c2.z=(fabsf(w2[2])>t2)?(w2[2]>0.f?1:-1):0; c2.w=(fabsf(w2[3])>t2)?(w2[3]>0.f?1:-1):0;
    c3.x=(fabsf(w3[0])>t3)?(w3[0]>0.f?1:-1):0; c3.y=(fabsf(w3[1])>t3)?(w3[1]>0.f?1:-1):0;
    c3.z=(fabsf(w3[2])>t3)?(w3[2]>0.f?1:-1):0; c3.w=(fabsf(w3[3])>t3)?(w3[3]>0.f?1:-1):0;
    *(char4*)(tern+(size_t)i0*4) = c0;
    *(char4*)(tern+(size_t)i1*4) = c1;
    *(char4*)(tern+(size_t)i2*4) = c2;
    *(char4*)(tern+(size_t)i3*4) = c3;
  }
}
__global__ __launch_bounds__(256) void k_f2b(const float* __restrict__ s, u16* __restrict__ d, int n4){
  int i = blockIdx.x*256+threadIdx.x;
  if (i<n4){
    float4 v=((const float4*)s)[i];
    ushort4 o; o.x=f2b(v.x); o.y=f2b(v.y); o.z=f2b(v.z); o.w=f2b(v.w);
    ((ushort4*)d)[i]=o;
  }
}

// ---------------- layernorm 1 ----------------
__global__ __launch_bounds__(256) void k_ln1(const float* __restrict__ x, const float* __restrict__ g,
                                             const float* __restrict__ b, u16* __restrict__ h){
  __shared__ float red[4];
  const int t=blockIdx.x, tid=threadIdx.x;
  float4 xv = ((const float4*)(x + (size_t)t*DM))[tid];
  float s  = xv.x+xv.y+xv.z+xv.w;
  float sq = xv.x*xv.x+xv.y*xv.y+xv.z*xv.z+xv.w*xv.w;
  float sum  = block_reduce_sum256(s, red);
  float sums = block_reduce_sum256(sq, red);
  float mu = sum*(1.0f/DM);
  float var = sums*(1.0f/DM) - mu*mu;
  float rstd = rsqrtf(var+1e-5f);
  float4 gv = ((const float4*)g)[tid];
  float4 bv = ((const float4*)b)[tid];
  ushort4 pk;
  pk.x = f2b((xv.x-mu)*rstd*gv.x+bv.x);
  pk.y = f2b((xv.y-mu)*rstd*gv.y+bv.y);
  pk.z = f2b((xv.z-mu)*rstd*gv.z+bv.z);
  pk.w = f2b((xv.w-mu)*rstd*gv.w+bv.w);
  ((ushort4*)(h + (size_t)t*DM))[tid] = pk;
}

// ---------------- bf16 MFMA GEMM: 128x128, BK=32, depth-2 prefetch + XCD swizzle ----------------
template<int MODE>
__global__ __launch_bounds__(256) void k_gemm(const u16* __restrict__ A, const u16* __restrict__ B,
                                              int K, int ldc, const float* __restrict__ bias,
                                              const float* __restrict__ resid, void* __restrict__ Cout,
                                              u16* __restrict__ vT){
  __shared__ u16 As[3][128*32];
  __shared__ u16 Bs[3][128*32];
  int bx, by; xcd_swizzle(bx, by);
  const int tid = threadIdx.x;
  const int w = tid>>6, lane = tid&63;
  const int m0 = by*128, n0 = bx*128;

  const int sr = lane>>2, ss = lane&3;
  const int ra0 = w*32 + sr, ra1 = ra0 + 16;
  const int kb0 = (ss ^ ((ra0>>1)&3))<<3;
  const int kb1 = (ss ^ ((ra1>>1)&3))<<3;
  const u16* pa0 = A + (size_t)(m0+ra0)*K + kb0;
  const u16* pa1 = A + (size_t)(m0+ra1)*K + kb1;
  const u16* pb0 = B + (size_t)(n0+ra0)*K + kb0;
  const u16* pb1 = B + (size_t)(n0+ra1)*K + kb1;
  const int lo0 = (w*32)*32, lo1 = lo0 + 16*32;

  const int wm = w>>1, wn = w&1;
  const int lr = lane&15, sl = lane>>4;
  int offA[4], offB[4];
  #pragma unroll
  for (int m=0;m<4;m++){ int r = wm*64 + m*16 + lr; offA[m] = r*64 + ((sl ^ ((r>>1)&3))<<4); }
  #pragma unroll
  for (int n=0;n<4;n++){ int r = wn*64 + n*16 + lr; offB[n] = r*64 + ((sl ^ ((r>>1)&3))<<4); }

  f32x4 acc[4][4] = {};
  const int NT = K>>5;
  GLD16(pa0, &As[0][lo0]); GLD16(pa1, &As[0][lo1]);
  GLD16(pb0, &Bs[0][lo0]); GLD16(pb1, &Bs[0][lo1]);
  pa0+=32; pa1+=32; pb0+=32; pb1+=32;
  GLD16(pa0, &As[1][lo0]); GLD16(pa1, &As[1][lo1]);
  GLD16(pb0, &Bs[1][lo0]); GLD16(pb1, &Bs[1][lo1]);
  pa0+=32; pa1+=32; pb0+=32; pb1+=32;

  int cur=0, nx2=2;
  for (int t=0;t<NT;t++){
    if (t+1<NT) asm volatile("s_waitcnt vmcnt(4) lgkmcnt(0)" ::: "memory");
    else        asm volatile("s_waitcnt vmcnt(0) lgkmcnt(0)" ::: "memory");
    __builtin_amdgcn_s_barrier();
    if (t+2<NT){
      GLD16(pa0, &As[nx2][lo0]); GLD16(pa1, &As[nx2][lo1]);
      GLD16(pb0, &Bs[nx2][lo0]); GLD16(pb1, &Bs[nx2][lo1]);
      pa0+=32; pa1+=32; pb0+=32; pb1+=32;
    }
    const char* Ab = (const char*)As[cur];
    const char* Bb = (const char*)Bs[cur];
    bf16x8 af[4], bfv[4];
    #pragma unroll
    for (int m=0;m<4;m++) af[m] = *(const bf16x8*)(Ab + offA[m]);
    #pragma unroll
    for (int n=0;n<4;n++) bfv[n] = *(const bf16x8*)(Bb + offB[n]);
    #pragma unroll
    for (int m=0;m<4;m++)
      #pragma unroll
      for (int n=0;n<4;n++)
        acc[m][n] = __builtin_amdgcn_mfma_f32_16x16x32_bf16(af[m], bfv[n], acc[m][n], 0, 0, 0);
    cur = (cur==2)?0:cur+1;
    nx2 = (nx2==2)?0:nx2+1;
  }

  const int rowg = lane>>4;
  #pragma unroll
  for (int m=0;m<4;m++){
    const int rbase = m0 + wm*64 + m*16 + rowg*4;
    #pragma unroll
    for (int n=0;n<4;n++){
      const int col = n0 + wn*64 + n*16 + lr;
      if (MODE==2){
        u16 pk4[4];
        #pragma unroll
        for (int j=0;j<4;j++){
          float v = acc[m][n][j] + bias[col];
          pk4[j] = f2b(v);
          ((u16*)Cout)[(size_t)(rbase+j)*ldc + col] = pk4[j];
        }
        if (col >= 2048){
          const int d = col-2048, hd = d>>6, dd = d&63;
          const int bb = rbase>>10, s = rbase&1023;
          uint2 pk; pk.x = (u32)pk4[0] | ((u32)pk4[1]<<16); pk.y = (u32)pk4[2] | ((u32)pk4[3]<<16);
          *(uint2*)(vT + (((size_t)((bb*16+hd)*64+dd))<<10) + s) = pk;
        }
      } else {
        #pragma unroll
        for (int j=0;j<4;j++){
          const size_t ci = (size_t)(rbase+j)*ldc + col;
          ((float*)Cout)[ci] = acc[m][n][j] + bias[col] + resid[ci];
        }
      }
    }
  }
}

// ---------------- i8 MFMA GEMM for MoE, depth-2 prefetch + XCD swizzle ----------------
template<bool GATHER>
__global__ __launch_bounds__(256) void k_gemm8(const signed char* __restrict__ A, const signed char* __restrict__ Ball,
                                               int K, int ldc,
                                               const int* __restrict__ tile2e, const int* __restrict__ rowmap,
                                               const float* __restrict__ rscale, u16* __restrict__ Cout){
  int bx, by; xcd_swizzle(bx, by);
  int e = tile2e[by];
  if (e < 0) return;
  const signed char* Bp = Ball + (size_t)e * MATSZ;
  __shared__ signed char As[3][128*64];
  __shared__ signed char Bs[3][128*64];
  const int tid = threadIdx.x;
  const int w = tid>>6, lane = tid&63;
  const int m0 = by*128, n0 = bx*128;

  const int sr = lane>>2, ss = lane&3;
  const int ra0 = w*32 + sr, ra1 = ra0 + 16;
  const int kb0 = (ss ^ ((ra0>>1)&3))<<4;
  const int kb1 = (ss ^ ((ra1>>1)&3))<<4;
  const signed char *pa0, *pa1;
  if (GATHER){
    int t0 = rowmap[m0+ra0]; if (t0<0) t0 = 0;
    int t1 = rowmap[m0+ra1]; if (t1<0) t1 = 0;
    pa0 = A + (size_t)t0*K + kb0;
    pa1 = A + (size_t)t1*K + kb1;
  } else {
    pa0 = A + (size_t)(m0+ra0)*K + kb0;
    pa1 = A + (size_t)(m0+ra1)*K + kb1;
  }
  const signed char* pb0 = Bp + (size_t)(n0+ra0)*K + kb0;
  const signed char* pb1 = Bp + (size_t)(n0+ra1)*K + kb1;
  const int lo0 = (w*32)*64, lo1 = lo0 + 16*64;

  const int wm = w>>1, wn = w&1;
  const int lr = lane&15, sl = lane>>4;
  int offA[4], offB[4];
  #pragma unroll
  for (int m=0;m<4;m++){ int r = wm*64 + m*16 + lr; offA[m] = r*64 + ((sl ^ ((r>>1)&3))<<4); }
  #pragma unroll
  for (int n=0;n<4;n++){ int r = wn*64 + n*16 + lr; offB[n] = r*64 + ((sl ^ ((r>>1)&3))<<4); }

  i32x4 acc[4][4] = {};
  const int NT = K>>6;
  GLD16(pa0, &As[0][lo0]); GLD16(pa1, &As[0][lo1]);
  GLD16(pb0, &Bs[0][lo0]); GLD16(pb1, &Bs[0][lo1]);
  pa0+=64; pa1+=64; pb0+=64; pb1+=64;
  GLD16(pa0, &As[1][lo0]); GLD16(pa1, &As[1][lo1]);
  GLD16(pb0, &Bs[1][lo0]); GLD16(pb1, &Bs[1][lo1]);
  pa0+=64; pa1+=64; pb0+=64; pb1+=64;

  int cur=0, nx2=2;
  for (int t=0;t<NT;t++){
    if (t+1<NT) asm volatile("s_waitcnt vmcnt(4) lgkmcnt(0)" ::: "memory");
    else        asm volatile("s_waitcnt vmcnt(0) lgkmcnt(0)" ::: "memory");
    __builtin_amdgcn_s_barrier();
    if (t+2<NT){
      GLD16(pa0, &As[nx2][lo0]); GLD16(pa1, &As[nx2][lo1]);
      GLD16(pb0, &Bs[nx2][lo0]); GLD16(pb1, &Bs[nx2][lo1]);
      pa0+=64; pa1+=64; pb0+=64; pb1+=64;
    }
    const char* Ab = (const char*)As[cur];
    const char* Bb = (const char*)Bs[cur];
    i32x4 af[4], bfv[4];
    #pragma unroll
    for (int m=0;m<4;m++) af[m] = *(const i32x4*)(Ab + offA[m]);
    #pragma unroll
    for (int n=0;n<4;n++) bfv[n] = *(const i32x4*)(Bb + offB[n]);
    #pragma unroll
    for (int m=0;m<4;m++)
      #pragma unroll
      for (int n=0;n<4;n++)
        acc[m][n] = __builtin_amdgcn_mfma_i32_16x16x64_i8(af[m], bfv[n], acc[m][n], 0, 0, 0);
    cur = (cur==2)?0:cur+1;
    nx2 = (nx2==2)?0:nx2+1;
  }

  const int rowg = lane>>4;
  #pragma unroll
  for (int m=0;m<4;m++){
    const int rbase = m0 + wm*64 + m*16 + rowg*4;
    #pragma unroll
    for (int n=0;n<4;n++){
      const int col = n0 + wn*64 + n*16 + lr;
      #pragma unroll
      for (int j=0;j<4;j++){
        float v = (float)acc[m][n][j] * rscale[rbase+j];
        Cout[(size_t)(rbase+j)*ldc + col] = f2b(v);
      }
    }
  }
}

// ---------------- MFMA flash attention (exp2 + defer-max + dbuf KV + setprio) ----------------
__global__ __launch_bounds__(256) void k_attn_mfma(const u16* __restrict__ qkv, const u16* __restrict__ vT,
                                                   u16* __restrict__ ob){
  __shared__ u16 Ks[2][64*64];
  __shared__ u16 Vs[2][64*64];
  __shared__ u16 Pa[4*16*64];
  const int qt=blockIdx.x, hh=blockIdx.y, bb=blockIdx.z;
  const int tid=threadIdx.x, w=tid>>6, lane=tid&63;
  const int g=lane>>4, lr=lane&15;
  const int srow8=lane>>3, sslot=lane&7;
  const float RTHR = 11.5f;   // log2 units

  bf16x8 qa[2];
  {
    const u16* qp = qkv + ((size_t)(bb*1024 + qt*64 + w*16 + lr))*3072 + hh*64 + g*8;
    #pragma unroll
    for (int c=0;c<2;c++){
      uint4 raw = *(const uint4*)(qp + c*32);
      float tv[8]; unpack8(raw,tv);
      union { u16 s[8]; bf16x8 v; } qq;
      #pragma unroll
      for (int i=0;i<8;i++) qq.s[i] = f2b(tv[i]*0.18033688f);
      qa[c] = qq.v;
    }
  }

  float mrow[4], lrow[4];
  #pragma unroll
  for (int j=0;j<4;j++){ mrow[j]=-1e30f; lrow[j]=0.f; }
  f32x4 acc_o[4] = {};

  char* pbuf = (char*)Pa + (w<<11);

  const int row0 = w*16 + srow8, row1 = row0 + 8;
  const int fs0 = (sslot ^ (row0&7))<<3;
  const int fs1 = (sslot ^ (row1&7))<<3;
  const int ldso0 = (w*16)*64, ldso1 = (w*16+8)*64;

  {
    const u16* gk0 = qkv + ((size_t)(bb*1024 + row0))*3072 + 1024 + hh*64 + fs0;
    const u16* gk1 = qkv + ((size_t)(bb*1024 + row1))*3072 + 1024 + hh*64 + fs1;
    GLD16(gk0, &Ks[0][ldso0]); GLD16(gk1, &Ks[0][ldso1]);
    const u16* gv0 = vT + ((size_t)((bb*16+hh)*64 + row0))*1024 + fs0;
    const u16* gv1 = vT + ((size_t)((bb*16+hh)*64 + row1))*1024 + fs1;
    GLD16(gv0, &Vs[0][ldso0]); GLD16(gv1, &Vs[0][ldso1]);
  }
  __syncthreads();

  for (int kt=0; kt<16; ++kt){
    if (kt+1<16){
      const int nb=(kt+1)&1;
      const u16* gk0 = qkv + ((size_t)(bb*1024 + (kt+1)*64 + row0))*3072 + 1024 + hh*64 + fs0;
      const u16* gk1 = qkv + ((size_t)(bb*1024 + (kt+1)*64 + row1))*3072 + 1024 + hh*64 + fs1;
      GLD16(gk0, &Ks[nb][ldso0]); GLD16(gk1, &Ks[nb][ldso1]);
      const u16* gv0 = vT + ((size_t)((bb*16+hh)*64 + row0))*1024 + (kt+1)*64 + fs0;
      const u16* gv1 = vT + ((size_t)((bb*16+hh)*64 + row1))*1024 + (kt+1)*64 + fs1;
      GLD16(gv0, &Vs[nb][ldso0]); GLD16(gv1, &Vs[nb][ldso1]);
    }
    const char* Kb = (const char*)Ks[kt&1];
    const char* Vb = (const char*)Vs[kt&1];

    f32x4 sacc[4] = {};
    __builtin_amdgcn_s_setprio(1);
    #pragma unroll
    for (int ct=0; ct<4; ct++){
      const int kv = ct*16 + lr;
      const char* krow = Kb + kv*128;
      bf16x8 kb0 = *(const bf16x8*)(krow + (((g  ) ^ (kv&7))<<4));
      bf16x8 kb1 = *(const bf16x8*)(krow + (((4+g) ^ (kv&7))<<4));
      sacc[ct] = __builtin_amdgcn_mfma_f32_16x16x32_bf16(qa[0], kb0, sacc[ct], 0,0,0);
      sacc[ct] = __builtin_amdgcn_mfma_f32_16x16x32_bf16(qa[1], kb1, sacc[ct], 0,0,0);
    }
    __builtin_amdgcn_s_setprio(0);

    float vmx[4]; bool okl = true;
    #pragma unroll
    for (int j=0;j<4;j++){
      vmx[j] = fmaxf(fmaxf(sacc[0][j],sacc[1][j]), fmaxf(sacc[2][j],sacc[3][j]));
      okl = okl && (vmx[j]-mrow[j] <= RTHR);
    }
    float psum[4] = {0.f,0.f,0.f,0.f};
    if (__all((int)okl)){
      #pragma unroll
      for (int ct=0; ct<4; ct++){
        #pragma unroll
        for (int j=0;j<4;j++){
          float p = exp2f(sacc[ct][j]-mrow[j]);
          psum[j] += p;
          const int q = g*4+j, k = ct*16+lr;
          *(u16*)(pbuf + q*128 + (((k>>3) ^ (q&7))<<4) + ((k&7)<<1)) = f2b(p);
        }
      }
      #pragma unroll
      for (int j=0;j<4;j++){
        float s = psum[j];
        s += __shfl_xor(s,1); s += __shfl_xor(s,2); s += __shfl_xor(s,4); s += __shfl_xor(s,8);
        lrow[j] += s;
      }
    } else {
      float mnew[4], corr[4];
      #pragma unroll
      for (int j=0;j<4;j++){
        float v = vmx[j];
        v = fmaxf(v, __shfl_xor(v,1));
        v = fmaxf(v, __shfl_xor(v,2));
        v = fmaxf(v, __shfl_xor(v,4));
        v = fmaxf(v, __shfl_xor(v,8));
        mnew[j] = fmaxf(mrow[j], v);
        corr[j] = exp2f(mrow[j]-mnew[j]);
        mrow[j] = mnew[j];
      }
      #pragma unroll
      for (int ct=0; ct<4; ct++){
        #pragma unroll
        for (int j=0;j<4;j++){
          float p = exp2f(sacc[ct][j]-mrow[j]);
          psum[j] += p;
          const int q = g*4+j, k = ct*16+lr;
          *(u16*)(pbuf + q*128 + (((k>>3) ^ (q&7))<<4) + ((k&7)<<1)) = f2b(p);
        }
      }
      #pragma unroll
      for (int j=0;j<4;j++){
        float s = psum[j];
        s += __shfl_xor(s,1); s += __shfl_xor(s,2); s += __shfl_xor(s,4); s += __shfl_xor(s,8);
        lrow[j] = lrow[j]*corr[j] + s;
      }
      #pragma unroll
      for (int ctd=0; ctd<4; ctd++)
        #pragma unroll
        for (int j=0;j<4;j++) acc_o[ctd][j] *= corr[j];
    }

    __builtin_amdgcn_s_setprio(1);
    #pragma unroll
    for (int c=0;c<2;c++){
      bf16x8 pa = *(const bf16x8*)(pbuf + lr*128 + (((c*4+g) ^ (lr&7))<<4));
      #pragma unroll
      for (int ctd=0; ctd<4; ctd++){
        const int d = ctd*16 + lr;
        bf16x8 vb = *(const bf16x8*)(Vb + d*128 + (((c*4+g) ^ (d&7))<<4));
        acc_o[ctd] = __builtin_amdgcn_mfma_f32_16x16x32_bf16(pa, vb, acc_o[ctd], 0,0,0);
      }
    }
    __builtin_amdgcn_s_setprio(0);
    __syncthreads();
  }

  #pragma unroll
  for (int j=0;j<4;j++){
    const float inv = 1.0f/lrow[j];
    const int row = bb*1024 + qt*64 + w*16 + g*4 + j;
    u16* op = ob + (size_t)row*DM + hh*64 + lr;
    #pragma unroll
    for (int ctd=0; ctd<4; ctd++) op[ctd*16] = f2b(acc_o[ctd][j]*inv);
  }
}

// ---------------- layernorm 2 + geometric router + i8 activation quant ----------------
__global__ __launch_bounds__(256) void k_ln2_router(const float* __restrict__ xa, const float* __restrict__ g,
                                                    const float* __restrict__ b, const float* __restrict__ rw,
                                                    signed char* __restrict__ xn8, int* __restrict__ eidx,
                                                    float* __restrict__ w1o, float* __restrict__ sbc){
  __shared__ float red[4];
  const int t=blockIdx.x, tid=threadIdx.x;
  float4 xv = ((const float4*)(xa + (size_t)t*DM))[tid];
  float s  = xv.x+xv.y+xv.z+xv.w;
  float sq = xv.x*xv.x+xv.y*xv.y+xv.z*xv.z+xv.w*xv.w;
  float sum  = block_reduce_sum256(s, red);
  float sums = block_reduce_sum256(sq, red);
  float mu = sum*(1.0f/DM);
  float var = sums*(1.0f/DM) - mu*mu;
  float rstd = rsqrtf(var+1e-5f);
  float4 gv = ((const float4*)g)[tid];
  float4 bv = ((const float4*)b)[tid];
  float y0=(xv.x-mu)*rstd*gv.x+bv.x;
  float y1=(xv.y-mu)*rstd*gv.y+bv.y;
  float y2=(xv.z-mu)*rstd*gv.z+bv.z;
  float y3=(xv.w-mu)*rstd*gv.w+bv.w;
  float4 r0=((const float4*)(rw+0*DM))[tid];
  float4 r1=((const float4*)(rw+1*DM))[tid];
  float4 r2=((const float4*)(rw+2*DM))[tid];
  float4 r3=((const float4*)(rw+3*DM))[tid];
  float nsq = y0*y0+y1*y1+y2*y2+y3*y3;
  float d0 = y0*r0.x+y1*r0.y+y2*r0.z+y3*r0.w;
  float d1 = y0*r1.x+y1*r1.y+y2*r1.z+y3*r1.w;
  float d2 = y0*r2.x+y1*r2.y+y2*r2.z+y3*r2.w;
  float d3 = y0*r3.x+y1*r3.y+y2*r3.z+y3*r3.w;
  float am = fmaxf(fmaxf(fabsf(y0),fabsf(y1)), fmaxf(fabsf(y2),fabsf(y3)));
  float AM = block_reduce_max256(am, red);
  float SQ = block_reduce_sum256(nsq, red);
  float D0 = block_reduce_sum256(d0, red);
  float D1 = block_reduce_sum256(d1, red);
  float D2 = block_reduce_sum256(d2, red);
  float D3 = block_reduce_sum256(d3, red);
  float qs = fmaxf(AM, 1e-12f) * (1.0f/127.0f);
  float inv = 1.0f/qs;
  char4 c;
  c.x = (signed char)__float2int_rn(y0*inv);
  c.y = (signed char)__float2int_rn(y1*inv);
  c.z = (signed char)__float2int_rn(y2*inv);
  c.w = (signed char)__float2int_rn(y3*inv);
  ((char4*)(xn8 + (size_t)t*DM))[tid] = c;
  if (tid==0){
    float n = fmaxf(sqrtf(D0*D0+D1*D1+D2*D2+D3*D3), 1e-12f);
    float h0=D0/n, h1=D1/n, h2=D2/n, h3=D3/n;
    float dot0 = 0.70710678f*(h0-h1);
    float dot1 = 0.70710678f*(h1-h2);
    float dot2 = h2;
    float dot3 = (-0.5f*h0+0.5f*h1+0.5f*h2+0.80901699f*h3)*0.8437966f;
    int ch = (int)(dot0>=0.f) + 2*(int)(dot1>=0.f) + 4*(int)(dot2>=0.f) + 8*(int)(dot3>=0.f);
    int e1 = ch & 7;
    int e2 = ((ch>>1)+1) & 7;
    if (e1==e2) e2=(e2+1)&7;
    float conf = fminf(fminf(fabsf(dot0),fabsf(dot1)), fminf(fabsf(dot2),fabsf(dot3)));
    eidx[2*t]=e1; eidx[2*t+1]=e2;
    w1o[t]=0.5f + 0.3f/(1.0f+__expf(-conf));
    sbc[t]= qs / (sqrtf(SQ*(1.0f/DM))+1e-8f);
  }
}

// ---------------- routing: histogram + offsets + scatter in ONE single-block kernel ----------------
__global__ __launch_bounds__(256) void k_route(const int* __restrict__ eidx, const float* __restrict__ sbc,
                                               int* __restrict__ tile2e, int* __restrict__ rowmap,
                                               float* __restrict__ srow, int* __restrict__ tokrow,
                                               int* __restrict__ ptot){
  __shared__ int cnt[8], pos[8];
  const int tid = threadIdx.x;
  if (tid<8) cnt[tid]=0;
  __syncthreads();
  for (int t=tid; t<TOK; t+=256){
    atomicAdd(&cnt[eidx[2*t]],1);
    atomicAdd(&cnt[eidx[2*t+1]],1);
  }
  __syncthreads();
  if (tid==0){
    int off=0;
    for (int e=0;e<8;e++){
      pos[e]=off;
      int pad = ((cnt[e]+127)>>7)<<7;
      int t0=off>>7, t1=(off+pad)>>7;
      for (int tt=t0;tt<t1;tt++) tile2e[tt]=e;
      off+=pad;
    }
    *ptot=off;
    for (int tt=off>>7; tt<PADTILES; tt++) tile2e[tt]=-1;
  }
  __syncthreads();
  for (int i=tid;i<PADROWS;i+=256){ rowmap[i]=-1; srow[i]=0.f; }
  __syncthreads();
  for (int t=tid; t<TOK; t+=256){
    int e1=eidx[2*t], e2=eidx[2*t+1];
    float s=sbc[t];
    int r1 = atomicAdd(&pos[e1],1);
    rowmap[r1]=t; srow[r1]=s; tokrow[2*t]=r1;
    int r2 = atomicAdd(&pos[e2],1);
    rowmap[r2]=t; srow[r2]=s; tokrow[2*t+1]=r2;
  }
}

// ---------------- GELU (exact) + per-row RMS normalize + i8 quant ----------------
__global__ __launch_bounds__(256) void k_gelu_rms(const u16* __restrict__ he, signed char* __restrict__ he8,
                                                  float* __restrict__ qd, const int* __restrict__ ptot){
  const int row = blockIdx.x;
  if (row >= *ptot) return;
  const u16* p = he + (size_t)row*DFF;
  const int tid=threadIdx.x;
  uint4 rw0 = ((const uint4*)p)[2*tid];
  uint4 rw1 = ((const uint4*)p)[2*tid+1];
  float v[16];
  unpack8(rw0, v); unpack8(rw1, v+8);
  float sq=0.f;
  #pragma unroll
  for (int q=0;q<16;q++){
    float xg = v[q];
    float ge = 0.5f*xg*(1.0f+erff(xg*0.70710678f));
    v[q]=ge; sq += ge*ge;
  }
  __shared__ float red[4];
  float SQ = block_reduce_sum256(sq, red);
  float s = 1.0f/(sqrtf(SQ*(1.0f/DFF))+1e-8f);
  float am = 0.f;
  #pragma unroll
  for (int q=0;q<16;q++){ v[q]*=s; am = fmaxf(am, fabsf(v[q])); }
  float AM = block_reduce_max256(am, red);
  float q8 = fmaxf(AM, 1e-12f) * (1.0f/127.0f);
  float inv = 1.0f/q8;
  union { signed char c[16]; uint4 u; } pk;
  #pragma unroll
  for (int q=0;q<16;q++) pk.c[q] = (signed char)__float2int_rn(v[q]*inv);
  ((uint4*)(he8 + (size_t)row*DFF))[tid] = pk.u;
  if (tid==0) qd[row] = q8;
}

// ---------------- combine ----------------
__global__ __launch_bounds__(256) void k_combine(const float* __restrict__ xa, const u16* __restrict__ y,
                                                 const int* __restrict__ tokrow, const float* __restrict__ w1,
                                                 float* __restrict__ out){
  const int t=blockIdx.x, tid=threadIdx.x;
  const int r1=tokrow[2*t], r2=tokrow[2*t+1];
  const float a = w1[t], bw = 1.0f-a;
  float4 xv = ((const float4*)(xa + (size_t)t*DM))[tid];
  ushort4 y1 = ((const ushort4*)(y + (size_t)r1*DM))[tid];
  ushort4 y2 = ((const ushort4*)(y + (size_t)r2*DM))[tid];
  float4 o;
  o.x = xv.x + a*b2f(y1.x) + bw*b2f(y2.x);
  o.y = xv.y + a*b2f(y1.y) + bw*b2f(y2.y);
  o.z = xv.z + a*b2f(y1.z) + bw*b2f(y2.z);
  o.w = xv.w + a*b2f(y1.w) + bw*b2f(y2.w);
  ((float4*)(out + (size_t)t*DM))[tid] = o;
}

extern "C" void kernel_launch(void* const* d_in, const int* in_sizes, int n_in,
                              void* d_out, int out_size, void* d_ws, size_t ws_size,
                              hipStream_t stream){
  (void)in_sizes; (void)n_in; (void)out_size; (void)ws_size;
  const float* x    = (const float*)d_in[0];
  const float* g1   = (const float*)d_in[1];
  const float* b1   = (const float*)d_in[2];
  const float* g2   = (const float*)d_in[3];
  const float* b2   = (const float*)d_in[4];
  const float* in_w = (const float*)d_in[5];
  const float* in_b = (const float*)d_in[6];
  const float* out_w= (const float*)d_in[7];
  const float* out_b= (const float*)d_in[8];
  const float* rw   = (const float*)d_in[9];
  const float* up_w = (const float*)d_in[10];
  const float* dn_w = (const float*)d_in[11];
  float* out = (float*)d_out;

  char* base = (char*)d_ws; size_t off=0;
  auto alloc = [&](size_t bytes)->char*{ char* p = base+off; off=(off+bytes+255)&~(size_t)255; return p; };
  u16* h      = (u16*)alloc((size_t)TOK*DM*2);
  u16* qkv    = (u16*)alloc((size_t)TOK*3072*2);
  u16* ob     = (u16*)alloc((size_t)TOK*DM*2);
  float* xattn= (float*)alloc((size_t)TOK*DM*4);
  signed char* xn8 = (signed char*)alloc((size_t)TOK*DM);
  signed char* tern8 = (signed char*)alloc((size_t)16*MATSZ);
  u16* wbf_in = (u16*)alloc((size_t)3145728*2);
  u16* wbf_out= (u16*)alloc((size_t)1048576*2);
  u16* vT     = (u16*)alloc((size_t)4*16*64*1024*2);
  u16* he     = (u16*)alloc((size_t)PADROWS*DFF*2);
  signed char* he8 = (signed char*)alloc((size_t)PADROWS*DFF);
  u16* y      = (u16*)alloc((size_t)PADROWS*DM*2);
  float* partials = (float*)alloc(8192*4);
  float* thr  = (float*)alloc(64);
  int* ptot   = (int*)alloc(64);
  int* eidx   = (int*)alloc((size_t)TOK*2*4);
  float* w1b  = (float*)alloc((size_t)TOK*4);
  float* sbc  = (float*)alloc((size_t)TOK*4);
  float* srow = (float*)alloc((size_t)PADROWS*4);
  float* qd   = (float*)alloc((size_t)PADROWS*4);
  int* tokrow = (int*)alloc((size_t)TOK*2*4);
  int* rowmap = (int*)alloc((size_t)PADROWS*4);
  int* tile2e = (int*)alloc(PADTILES*4);

  k_absum1<<<8192,256,0,stream>>>(up_w, dn_w, partials);
  k_absum2<<<1,256,0,stream>>>(partials, thr);
  k_ternarize<<<8192,256,0,stream>>>(up_w, dn_w, thr, tern8);
  k_f2b<<<3072,256,0,stream>>>(in_w, wbf_in, 786432);
  k_f2b<<<1024,256,0,stream>>>(out_w, wbf_out, 262144);
  k_ln1<<<TOK,256,0,stream>>>(x, g1, b1, h);
  k_gemm<2><<<dim3(24,32),256,0,stream>>>(h, wbf_in, 1024, 3072, in_b, nullptr, qkv, vT);
  k_attn_mfma<<<dim3(16,16,4),256,0,stream>>>(qkv, vT, ob);
  k_gemm<3><<<dim3(8,32),256,0,stream>>>(ob, wbf_out, 1024, 1024, out_b, x, xattn, nullptr);
  k_ln2_router<<<TOK,256,0,stream>>>(xattn, g2, b2, rw, xn8, eidx, w1b, sbc);
  k_route<<<1,256,0,stream>>>(eidx, sbc, tile2e, rowmap, srow, tokrow, ptot);
  k_gemm8<true><<<dim3(32,PADTILES),256,0,stream>>>(xn8, tern8, 1024, 4096,
      tile2e, rowmap, srow, he);
  k_gelu_rms<<<PADROWS,256,0,stream>>>(he, he8, qd, ptot);
  k_gemm8<false><<<dim3(8,PADTILES),256,0,stream>>>(he8, tern8 + (size_t)8*MATSZ, 4096, 1024,
      tile2e, nullptr, qd, y);
  k_combine<<<TOK,256,0,stream>>>(xattn, y, tokrow, w1b, out);
}

// Round 12
// 421.772 us; speedup vs baseline: 1.2963x; 1.0035x over previous
//
#include <hip/hip_runtime.h>
#include <math.h>

#define TOK 4096
#define DM 1024
#define DFF 4096
#define MATSZ 4194304   // 4096*1024 elements per expert matrix
#define PADROWS 9216
#define PADTILES 72

typedef unsigned short u16;
typedef unsigned int   u32;
typedef __attribute__((ext_vector_type(8))) __bf16 bf16x8;
typedef __attribute__((ext_vector_type(4))) float  f32x4;
typedef __attribute__((ext_vector_type(4))) int    i32x4;
typedef __attribute__((ext_vector_type(4))) float  f4v;

#define GLD16(gp, lp) __builtin_amdgcn_global_load_lds( \
    (const __attribute__((address_space(1))) void*)(gp), \
    (__attribute__((address_space(3))) void*)(lp), 16, 0, 0)

// XCD-aware bijective block swizzle (nwg % 8 == 0)
__device__ __forceinline__ void xcd_swizzle(int &bx, int &by){
  const int gx = gridDim.x;
  const int nwg = gx * gridDim.y;
  int flat = blockIdx.y * gx + blockIdx.x;
  int wg = (flat & 7) * (nwg >> 3) + (flat >> 3);
  bx = wg % gx; by = wg / gx;
}

// ---------------- helpers ----------------
__device__ __forceinline__ float b2f(u16 u){ return __uint_as_float(((u32)u)<<16); }
__device__ __forceinline__ u16 f2b(float f){
  u32 i = __float_as_uint(f);
  u32 r = i + 0x7fffu + ((i>>16)&1u);
  return (u16)(r>>16);
}
__device__ __forceinline__ void unpack8(uint4 rw, float* dst){
  u32 u0=rw.x,u1=rw.y,u2=rw.z,u3=rw.w;
  dst[0]=__uint_as_float(u0<<16); dst[1]=__uint_as_float(u0&0xffff0000u);
  dst[2]=__uint_as_float(u1<<16); dst[3]=__uint_as_float(u1&0xffff0000u);
  dst[4]=__uint_as_float(u2<<16); dst[5]=__uint_as_float(u2&0xffff0000u);
  dst[6]=__uint_as_float(u3<<16); dst[7]=__uint_as_float(u3&0xffff0000u);
}
__device__ __forceinline__ float block_reduce_sum256(float v, float* red){
  #pragma unroll
  for (int off=32; off>0; off>>=1) v += __shfl_down(v, off);
  __syncthreads();
  if ((threadIdx.x & 63)==0) red[threadIdx.x>>6] = v;
  __syncthreads();
  return red[0]+red[1]+red[2]+red[3];
}
__device__ __forceinline__ float block_reduce_max256(float v, float* red){
  #pragma unroll
  for (int off=32; off>0; off>>=1) v = fmaxf(v, __shfl_down(v, off));
  __syncthreads();
  if ((threadIdx.x & 63)==0) red[threadIdx.x>>6] = v;
  __syncthreads();
  return fmaxf(fmaxf(red[0],red[1]), fmaxf(red[2],red[3]));
}

// ---------------- ternarize (alpha = mean|w| per expert matrix) ----------------
__global__ __launch_bounds__(256) void k_absum1(const float* __restrict__ up, const float* __restrict__ dn,
                                                float* __restrict__ partials){
  const int b = blockIdx.x;                 // 8192 blocks; 512 per matrix
  const size_t f4i = (size_t)b*2048;
  const f4v* s4 = (b < 4096) ? ((const f4v*)up + f4i) : ((const f4v*)dn + (f4i - 8388608));
  const int tid = threadIdx.x;
  float a0=0.f,a1=0.f,a2=0.f,a3=0.f;
  #pragma unroll
  for (int i=0;i<2;i++){
    f4v v0 = __builtin_nontemporal_load(s4 + i*1024 + tid);
    f4v v1 = __builtin_nontemporal_load(s4 + i*1024 + tid + 256);
    f4v v2 = __builtin_nontemporal_load(s4 + i*1024 + tid + 512);
    f4v v3 = __builtin_nontemporal_load(s4 + i*1024 + tid + 768);
    a0 += fabsf(v0[0])+fabsf(v0[1])+fabsf(v0[2])+fabsf(v0[3]);
    a1 += fabsf(v1[0])+fabsf(v1[1])+fabsf(v1[2])+fabsf(v1[3]);
    a2 += fabsf(v2[0])+fabsf(v2[1])+fabsf(v2[2])+fabsf(v2[3]);
    a3 += fabsf(v3[0])+fabsf(v3[1])+fabsf(v3[2])+fabsf(v3[3]);
  }
  __shared__ float red[4];
  float tot = block_reduce_sum256((a0+a1)+(a2+a3), red);
  if (tid==0) partials[b]=tot;
}
__global__ void k_absum2(const float* __restrict__ partials, float* __restrict__ thr){
  const int t=threadIdx.x;            // 256 threads: 16 per matrix
  const int m=t>>4, k=t&15;
  float s=0.f;
  for (int i=0;i<32;i++) s += partials[m*512 + k + i*16];
  s += __shfl_xor(s,1); s += __shfl_xor(s,2); s += __shfl_xor(s,4); s += __shfl_xor(s,8);
  if (k==0) thr[m]=0.5f*s/4194304.0f;
}
__global__ __launch_bounds__(256) void k_ternarize(const float* __restrict__ up, const float* __restrict__ dn,
                                                   const float* __restrict__ thr, signed char* __restrict__ tern){
  const int nvec = 16777216; // 67.1M / 4
  for (int i0 = blockIdx.x*1024 + threadIdx.x; i0 < nvec; i0 += gridDim.x*1024){
    const int i1 = i0 + 256, i2 = i0 + 512, i3 = i0 + 768;
    f4v w0 = (i0 < 8388608) ? __builtin_nontemporal_load((const f4v*)up + i0) : __builtin_nontemporal_load((const f4v*)dn + (i0-8388608));
    f4v w1 = (i1 < 8388608) ? __builtin_nontemporal_load((const f4v*)up + i1) : __builtin_nontemporal_load((const f4v*)dn + (i1-8388608));
    f4v w2 = (i2 < 8388608) ? __builtin_nontemporal_load((const f4v*)up + i2) : __builtin_nontemporal_load((const f4v*)dn + (i2-8388608));
    f4v w3 = (i3 < 8388608) ? __builtin_nontemporal_load((const f4v*)up + i3) : __builtin_nontemporal_load((const f4v*)dn + (i3-8388608));
    float t0 = thr[(int)(((size_t)i0*4)>>22)];
    float t1 = thr[(int)(((size_t)i1*4)>>22)];
    float t2 = thr[(int)(((size_t)i2*4)>>22)];
    float t3 = thr[(int)(((size_t)i3*4)>>22)];
    char4 c0, c1, c2, c3;
    c0.x=(fabsf(w0[0])>t0)?(w0[0]>0.f?1:-1):0; c0.y=(fabsf(w0[1])>t0)?(w0[1]>0.f?1:-1):0;
    c0.z=(fabsf(w0[2])>t0)?(w0[2]>0.f?1:-1):0; c0.w=(fabsf(w0[3])>t0)?(w0[3]>0.f?1:-1):0;
    c1.x=(fabsf(w1[0])>t1)?(w1[0]>0.f?1:-1):0; c1.y=(fabsf(w1[1])>t1)?(w1[1]>0.f?1:-1):0;
    c1.z=(fabsf(w1[2])>t1)?(w1[2]>0.f?1:-1):0; c1.w=(fabsf(w1[3])>t1)?(w1[3]>0.f?1:-1):0;
    c2.x=(fabsf(w2[0])>t2)?(w2[0]>0.f?1:-1):0; c2.y=(fabsf(w2[1])>t2)?(w2[1]>0.f?1:-1):0;
    c2.z=(fabsf(w2[2])>t2)?(w2[2]>0.f?1:-1):0; c2.w=(fabsf(w2[3])>t2)?(w2[3]>0.f?1:-1):0;
    c3.x=(fabsf(w3[0])>t3)?(w3[0]>0.f?1:-1):0; c3.y=(fabsf(w3[1])>t3)?(w3[1]>0.f?1:-1):0;
    c3.z=(fabsf(w3[2])>t3)?(w3[2]>0.f?1:-1):0; c3.w=(fabsf(w3[3])>t3)?(w3[3]>0.f?1:-1):0;
    *(char4*)(tern+(size_t)i0*4) = c0;
    *(char4*)(tern+(size_t)i1*4) = c1;
    *(char4*)(tern+(size_t)i2*4) = c2;
    *(char4*)(tern+(size_t)i3*4) = c3;
  }
}
__global__ __launch_bounds__(256) void k_f2b(const float* __restrict__ s, u16* __restrict__ d, int n4){
  int i = blockIdx.x*256+threadIdx.x;
  if (i<n4){
    float4 v=((const float4*)s)[i];
    ushort4 o; o.x=f2b(v.x); o.y=f2b(v.y); o.z=f2b(v.z); o.w=f2b(v.w);
    ((ushort4*)d)[i]=o;
  }
}

// ---------------- layernorm 1 ----------------
__global__ __launch_bounds__(256) void k_ln1(const float* __restrict__ x, const float* __restrict__ g,
                                             const float* __restrict__ b, u16* __restrict__ h){
  __shared__ float red[4];
  const int t=blockIdx.x, tid=threadIdx.x;
  float4 xv = ((const float4*)(x + (size_t)t*DM))[tid];
  float s  = xv.x+xv.y+xv.z+xv.w;
  float sq = xv.x*xv.x+xv.y*xv.y+xv.z*xv.z+xv.w*xv.w;
  float sum  = block_reduce_sum256(s, red);
  float sums = block_reduce_sum256(sq, red);
  float mu = sum*(1.0f/DM);
  float var = sums*(1.0f/DM) - mu*mu;
  float rstd = rsqrtf(var+1e-5f);
  float4 gv = ((const float4*)g)[tid];
  float4 bv = ((const float4*)b)[tid];
  ushort4 pk;
  pk.x = f2b((xv.x-mu)*rstd*gv.x+bv.x);
  pk.y = f2b((xv.y-mu)*rstd*gv.y+bv.y);
  pk.z = f2b((xv.z-mu)*rstd*gv.z+bv.z);
  pk.w = f2b((xv.w-mu)*rstd*gv.w+bv.w);
  ((ushort4*)(h + (size_t)t*DM))[tid] = pk;
}

// ---------------- bf16 MFMA GEMM: 128x128, BK=32, 2-buffer + counted vmcnt + 2 barriers ----------------
// iter t: {issue stage(t+1) -> buf[(t+1)&1]} wait vmcnt(4) [stage(t) done] -> barrier(publish)
//         -> compute buf[t&1] -> barrier(retire: next iter may overwrite buf[t&1]... at t+2)
// LDS 32KB -> 5 blocks/CU (was 48KB/3): occupancy lever, keeps 1-iter latency cover.
template<int MODE>
__global__ __launch_bounds__(256) void k_gemm(const u16* __restrict__ A, const u16* __restrict__ B,
                                              int K, int ldc, const float* __restrict__ bias,
                                              const float* __restrict__ resid, void* __restrict__ Cout,
                                              u16* __restrict__ vT){
  __shared__ u16 As[2][128*32];
  __shared__ u16 Bs[2][128*32];
  int bx, by; xcd_swizzle(bx, by);
  const int tid = threadIdx.x;
  const int w = tid>>6, lane = tid&63;
  const int m0 = by*128, n0 = bx*128;

  const int sr = lane>>2, ss = lane&3;
  const int ra0 = w*32 + sr, ra1 = ra0 + 16;
  const int kb0 = (ss ^ ((ra0>>1)&3))<<3;
  const int kb1 = (ss ^ ((ra1>>1)&3))<<3;
  const u16* pa0 = A + (size_t)(m0+ra0)*K + kb0;
  const u16* pa1 = A + (size_t)(m0+ra1)*K + kb1;
  const u16* pb0 = B + (size_t)(n0+ra0)*K + kb0;
  const u16* pb1 = B + (size_t)(n0+ra1)*K + kb1;
  const int lo0 = (w*32)*32, lo1 = lo0 + 16*32;

  const int wm = w>>1, wn = w&1;
  const int lr = lane&15, sl = lane>>4;
  int offA[4], offB[4];
  #pragma unroll
  for (int m=0;m<4;m++){ int r = wm*64 + m*16 + lr; offA[m] = r*64 + ((sl ^ ((r>>1)&3))<<4); }
  #pragma unroll
  for (int n=0;n<4;n++){ int r = wn*64 + n*16 + lr; offB[n] = r*64 + ((sl ^ ((r>>1)&3))<<4); }

  f32x4 acc[4][4] = {};
  const int NT = K>>5;
  // prologue: stage tile 0 into buffer 0
  GLD16(pa0, &As[0][lo0]); GLD16(pa1, &As[0][lo1]);
  GLD16(pb0, &Bs[0][lo0]); GLD16(pb1, &Bs[0][lo1]);
  pa0+=32; pa1+=32; pb0+=32; pb1+=32;

  for (int t=0;t<NT;t++){
    if (t+1<NT){
      const int nb=(t+1)&1;
      GLD16(pa0, &As[nb][lo0]); GLD16(pa1, &As[nb][lo1]);
      GLD16(pb0, &Bs[nb][lo0]); GLD16(pb1, &Bs[nb][lo1]);
      pa0+=32; pa1+=32; pb0+=32; pb1+=32;
      asm volatile("s_waitcnt vmcnt(4)" ::: "memory");
    } else {
      asm volatile("s_waitcnt vmcnt(0)" ::: "memory");
    }
    __builtin_amdgcn_s_barrier();   // publish stage(t)
    const char* Ab = (const char*)As[t&1];
    const char* Bb = (const char*)Bs[t&1];
    bf16x8 af[4], bfv[4];
    #pragma unroll
    for (int m=0;m<4;m++) af[m] = *(const bf16x8*)(Ab + offA[m]);
    #pragma unroll
    for (int n=0;n<4;n++) bfv[n] = *(const bf16x8*)(Bb + offB[n]);
    #pragma unroll
    for (int m=0;m<4;m++)
      #pragma unroll
      for (int n=0;n<4;n++)
        acc[m][n] = __builtin_amdgcn_mfma_f32_16x16x32_bf16(af[m], bfv[n], acc[m][n], 0, 0, 0);
    __builtin_amdgcn_s_barrier();   // retire reads of buf[t&1]
  }

  const int rowg = lane>>4;
  #pragma unroll
  for (int m=0;m<4;m++){
    const int rbase = m0 + wm*64 + m*16 + rowg*4;
    #pragma unroll
    for (int n=0;n<4;n++){
      const int col = n0 + wn*64 + n*16 + lr;
      if (MODE==2){
        u16 pk4[4];
        #pragma unroll
        for (int j=0;j<4;j++){
          float v = acc[m][n][j] + bias[col];
          pk4[j] = f2b(v);
          ((u16*)Cout)[(size_t)(rbase+j)*ldc + col] = pk4[j];
        }
        if (col >= 2048){
          const int d = col-2048, hd = d>>6, dd = d&63;
          const int bb = rbase>>10, s = rbase&1023;
          uint2 pk; pk.x = (u32)pk4[0] | ((u32)pk4[1]<<16); pk.y = (u32)pk4[2] | ((u32)pk4[3]<<16);
          *(uint2*)(vT + (((size_t)((bb*16+hd)*64+dd))<<10) + s) = pk;
        }
      } else {
        #pragma unroll
        for (int j=0;j<4;j++){
          const size_t ci = (size_t)(rbase+j)*ldc + col;
          ((float*)Cout)[ci] = acc[m][n][j] + bias[col] + resid[ci];
        }
      }
    }
  }
}

// ---------------- i8 MFMA GEMM for MoE: 2-buffer + counted vmcnt + 2 barriers ----------------
template<bool GATHER>
__global__ __launch_bounds__(256) void k_gemm8(const signed char* __restrict__ A, const signed char* __restrict__ Ball,
                                               int K, int ldc,
                                               const int* __restrict__ tile2e, const int* __restrict__ rowmap,
                                               const float* __restrict__ rscale, u16* __restrict__ Cout){
  int bx, by; xcd_swizzle(bx, by);
  int e = tile2e[by];
  if (e < 0) return;
  const signed char* Bp = Ball + (size_t)e * MATSZ;
  __shared__ signed char As[2][128*64];
  __shared__ signed char Bs[2][128*64];
  const int tid = threadIdx.x;
  const int w = tid>>6, lane = tid&63;
  const int m0 = by*128, n0 = bx*128;

  const int sr = lane>>2, ss = lane&3;
  const int ra0 = w*32 + sr, ra1 = ra0 + 16;
  const int kb0 = (ss ^ ((ra0>>1)&3))<<4;
  const int kb1 = (ss ^ ((ra1>>1)&3))<<4;
  const signed char *pa0, *pa1;
  if (GATHER){
    int t0 = rowmap[m0+ra0]; if (t0<0) t0 = 0;
    int t1 = rowmap[m0+ra1]; if (t1<0) t1 = 0;
    pa0 = A + (size_t)t0*K + kb0;
    pa1 = A + (size_t)t1*K + kb1;
  } else {
    pa0 = A + (size_t)(m0+ra0)*K + kb0;
    pa1 = A + (size_t)(m0+ra1)*K + kb1;
  }
  const signed char* pb0 = Bp + (size_t)(n0+ra0)*K + kb0;
  const signed char* pb1 = Bp + (size_t)(n0+ra1)*K + kb1;
  const int lo0 = (w*32)*64, lo1 = lo0 + 16*64;

  const int wm = w>>1, wn = w&1;
  const int lr = lane&15, sl = lane>>4;
  int offA[4], offB[4];
  #pragma unroll
  for (int m=0;m<4;m++){ int r = wm*64 + m*16 + lr; offA[m] = r*64 + ((sl ^ ((r>>1)&3))<<4); }
  #pragma unroll
  for (int n=0;n<4;n++){ int r = wn*64 + n*16 + lr; offB[n] = r*64 + ((sl ^ ((r>>1)&3))<<4); }

  i32x4 acc[4][4] = {};
  const int NT = K>>6;
  GLD16(pa0, &As[0][lo0]); GLD16(pa1, &As[0][lo1]);
  GLD16(pb0, &Bs[0][lo0]); GLD16(pb1, &Bs[0][lo1]);
  pa0+=64; pa1+=64; pb0+=64; pb1+=64;

  for (int t=0;t<NT;t++){
    if (t+1<NT){
      const int nb=(t+1)&1;
      GLD16(pa0, &As[nb][lo0]); GLD16(pa1, &As[nb][lo1]);
      GLD16(pb0, &Bs[nb][lo0]); GLD16(pb1, &Bs[nb][lo1]);
      pa0+=64; pa1+=64; pb0+=64; pb1+=64;
      asm volatile("s_waitcnt vmcnt(4)" ::: "memory");
    } else {
      asm volatile("s_waitcnt vmcnt(0)" ::: "memory");
    }
    __builtin_amdgcn_s_barrier();   // publish stage(t)
    const char* Ab = (const char*)As[t&1];
    const char* Bb = (const char*)Bs[t&1];
    i32x4 af[4], bfv[4];
    #pragma unroll
    for (int m=0;m<4;m++) af[m] = *(const i32x4*)(Ab + offA[m]);
    #pragma unroll
    for (int n=0;n<4;n++) bfv[n] = *(const i32x4*)(Bb + offB[n]);
    #pragma unroll
    for (int m=0;m<4;m++)
      #pragma unroll
      for (int n=0;n<4;n++)
        acc[m][n] = __builtin_amdgcn_mfma_i32_16x16x64_i8(af[m], bfv[n], acc[m][n], 0, 0, 0);
    __builtin_amdgcn_s_barrier();   // retire reads of buf[t&1]
  }

  const int rowg = lane>>4;
  #pragma unroll
  for (int m=0;m<4;m++){
    const int rbase = m0 + wm*64 + m*16 + rowg*4;
    #pragma unroll
    for (int n=0;n<4;n++){
      const int col = n0 + wn*64 + n*16 + lr;
      #pragma unroll
      for (int j=0;j<4;j++){
        float v = (float)acc[m][n][j] * rscale[rbase+j];
        Cout[(size_t)(rbase+j)*ldc + col] = f2b(v);
      }
    }
  }
}

// ---------------- MFMA flash attention (exp2 + defer-max + dbuf KV + setprio) ----------------
__global__ __launch_bounds__(256) void k_attn_mfma(const u16* __restrict__ qkv, const u16* __restrict__ vT,
                                                   u16* __restrict__ ob){
  __shared__ u16 Ks[2][64*64];
  __shared__ u16 Vs[2][64*64];
  __shared__ u16 Pa[4*16*64];
  const int qt=blockIdx.x, hh=blockIdx.y, bb=blockIdx.z;
  const int tid=threadIdx.x, w=tid>>6, lane=tid&63;
  const int g=lane>>4, lr=lane&15;
  const int srow8=lane>>3, sslot=lane&7;
  const float RTHR = 11.5f;   // log2 units

  bf16x8 qa[2];
  {
    const u16* qp = qkv + ((size_t)(bb*1024 + qt*64 + w*16 + lr))*3072 + hh*64 + g*8;
    #pragma unroll
    for (int c=0;c<2;c++){
      uint4 raw = *(const uint4*)(qp + c*32);
      float tv[8]; unpack8(raw,tv);
      union { u16 s[8]; bf16x8 v; } qq;
      #pragma unroll
      for (int i=0;i<8;i++) qq.s[i] = f2b(tv[i]*0.18033688f);
      qa[c] = qq.v;
    }
  }

  float mrow[4], lrow[4];
  #pragma unroll
  for (int j=0;j<4;j++){ mrow[j]=-1e30f; lrow[j]=0.f; }
  f32x4 acc_o[4] = {};

  char* pbuf = (char*)Pa + (w<<11);

  const int row0 = w*16 + srow8, row1 = row0 + 8;
  const int fs0 = (sslot ^ (row0&7))<<3;
  const int fs1 = (sslot ^ (row1&7))<<3;
  const int ldso0 = (w*16)*64, ldso1 = (w*16+8)*64;

  {
    const u16* gk0 = qkv + ((size_t)(bb*1024 + row0))*3072 + 1024 + hh*64 + fs0;
    const u16* gk1 = qkv + ((size_t)(bb*1024 + row1))*3072 + 1024 + hh*64 + fs1;
    GLD16(gk0, &Ks[0][ldso0]); GLD16(gk1, &Ks[0][ldso1]);
    const u16* gv0 = vT + ((size_t)((bb*16+hh)*64 + row0))*1024 + fs0;
    const u16* gv1 = vT + ((size_t)((bb*16+hh)*64 + row1))*1024 + fs1;
    GLD16(gv0, &Vs[0][ldso0]); GLD16(gv1, &Vs[0][ldso1]);
  }
  __syncthreads();

  for (int kt=0; kt<16; ++kt){
    if (kt+1<16){
      const int nb=(kt+1)&1;
      const u16* gk0 = qkv + ((size_t)(bb*1024 + (kt+1)*64 + row0))*3072 + 1024 + hh*64 + fs0;
      const u16* gk1 = qkv + ((size_t)(bb*1024 + (kt+1)*64 + row1))*3072 + 1024 + hh*64 + fs1;
      GLD16(gk0, &Ks[nb][ldso0]); GLD16(gk1, &Ks[nb][ldso1]);
      const u16* gv0 = vT + ((size_t)((bb*16+hh)*64 + row0))*1024 + (kt+1)*64 + fs0;
      const u16* gv1 = vT + ((size_t)((bb*16+hh)*64 + row1))*1024 + (kt+1)*64 + fs1;
      GLD16(gv0, &Vs[nb][ldso0]); GLD16(gv1, &Vs[nb][ldso1]);
    }
    const char* Kb = (const char*)Ks[kt&1];
    const char* Vb = (const char*)Vs[kt&1];

    f32x4 sacc[4] = {};
    __builtin_amdgcn_s_setprio(1);
    #pragma unroll
    for (int ct=0; ct<4; ct++){
      const int kv = ct*16 + lr;
      const char* krow = Kb + kv*128;
      bf16x8 kb0 = *(const bf16x8*)(krow + (((g  ) ^ (kv&7))<<4));
      bf16x8 kb1 = *(const bf16x8*)(krow + (((4+g) ^ (kv&7))<<4));
      sacc[ct] = __builtin_amdgcn_mfma_f32_16x16x32_bf16(qa[0], kb0, sacc[ct], 0,0,0);
      sacc[ct] = __builtin_amdgcn_mfma_f32_16x16x32_bf16(qa[1], kb1, sacc[ct], 0,0,0);
    }
    __builtin_amdgcn_s_setprio(0);

    float vmx[4]; bool okl = true;
    #pragma unroll
    for (int j=0;j<4;j++){
      vmx[j] = fmaxf(fmaxf(sacc[0][j],sacc[1][j]), fmaxf(sacc[2][j],sacc[3][j]));
      okl = okl && (vmx[j]-mrow[j] <= RTHR);
    }
    float psum[4] = {0.f,0.f,0.f,0.f};
    if (__all((int)okl)){
      #pragma unroll
      for (int ct=0; ct<4; ct++){
        #pragma unroll
        for (int j=0;j<4;j++){
          float p = exp2f(sacc[ct][j]-mrow[j]);
          psum[j] += p;
          const int q = g*4+j, k = ct*16+lr;
          *(u16*)(pbuf + q*128 + (((k>>3) ^ (q&7))<<4) + ((k&7)<<1)) = f2b(p);
        }
      }
      #pragma unroll
      for (int j=0;j<4;j++){
        float s = psum[j];
        s += __shfl_xor(s,1); s += __shfl_xor(s,2); s += __shfl_xor(s,4); s += __shfl_xor(s,8);
        lrow[j] += s;
      }
    } else {
      float mnew[4], corr[4];
      #pragma unroll
      for (int j=0;j<4;j++){
        float v = vmx[j];
        v = fmaxf(v, __shfl_xor(v,1));
        v = fmaxf(v, __shfl_xor(v,2));
        v = fmaxf(v, __shfl_xor(v,4));
        v = fmaxf(v, __shfl_xor(v,8));
        mnew[j] = fmaxf(mrow[j], v);
        corr[j] = exp2f(mrow[j]-mnew[j]);
        mrow[j] = mnew[j];
      }
      #pragma unroll
      for (int ct=0; ct<4; ct++){
        #pragma unroll
        for (int j=0;j<4;j++){
          float p = exp2f(sacc[ct][j]-mrow[j]);
          psum[j] += p;
          const int q = g*4+j, k = ct*16+lr;
          *(u16*)(pbuf + q*128 + (((k>>3) ^ (q&7))<<4) + ((k&7)<<1)) = f2b(p);
        }
      }
      #pragma unroll
      for (int j=0;j<4;j++){
        float s = psum[j];
        s += __shfl_xor(s,1); s += __shfl_xor(s,2); s += __shfl_xor(s,4); s += __shfl_xor(s,8);
        lrow[j] = lrow[j]*corr[j] + s;
      }
      #pragma unroll
      for (int ctd=0; ctd<4; ctd++)
        #pragma unroll
        for (int j=0;j<4;j++) acc_o[ctd][j] *= corr[j];
    }

    __builtin_amdgcn_s_setprio(1);
    #pragma unroll
    for (int c=0;c<2;c++){
      bf16x8 pa = *(const bf16x8*)(pbuf + lr*128 + (((c*4+g) ^ (lr&7))<<4));
      #pragma unroll
      for (int ctd=0; ctd<4; ctd++){
        const int d = ctd*16 + lr;
        bf16x8 vb = *(const bf16x8*)(Vb + d*128 + (((c*4+g) ^ (d&7))<<4));
        acc_o[ctd] = __builtin_amdgcn_mfma_f32_16x16x32_bf16(pa, vb, acc_o[ctd], 0,0,0);
      }
    }
    __builtin_amdgcn_s_setprio(0);
    __syncthreads();
  }

  #pragma unroll
  for (int j=0;j<4;j++){
    const float inv = 1.0f/lrow[j];
    const int row = bb*1024 + qt*64 + w*16 + g*4 + j;
    u16* op = ob + (size_t)row*DM + hh*64 + lr;
    #pragma unroll
    for (int ctd=0; ctd<4; ctd++) op[ctd*16] = f2b(acc_o[ctd][j]*inv);
  }
}

// ---------------- layernorm 2 + geometric router + i8 activation quant ----------------
__global__ __launch_bounds__(256) void k_ln2_router(const float* __restrict__ xa, const float* __restrict__ g,
                                                    const float* __restrict__ b, const float* __restrict__ rw,
                                                    signed char* __restrict__ xn8, int* __restrict__ eidx,
                                                    float* __restrict__ w1o, float* __restrict__ sbc){
  __shared__ float red[4];
  const int t=blockIdx.x, tid=threadIdx.x;
  float4 xv = ((const float4*)(xa + (size_t)t*DM))[tid];
  float s  = xv.x+xv.y+xv.z+xv.w;
  float sq = xv.x*xv.x+xv.y*xv.y+xv.z*xv.z+xv.w*xv.w;
  float sum  = block_reduce_sum256(s, red);
  float sums = block_reduce_sum256(sq, red);
  float mu = sum*(1.0f/DM);
  float var = sums*(1.0f/DM) - mu*mu;
  float rstd = rsqrtf(var+1e-5f);
  float4 gv = ((const float4*)g)[tid];
  float4 bv = ((const float4*)b)[tid];
  float y0=(xv.x-mu)*rstd*gv.x+bv.x;
  float y1=(xv.y-mu)*rstd*gv.y+bv.y;
  float y2=(xv.z-mu)*rstd*gv.z+bv.z;
  float y3=(xv.w-mu)*rstd*gv.w+bv.w;
  float4 r0=((const float4*)(rw+0*DM))[tid];
  float4 r1=((const float4*)(rw+1*DM))[tid];
  float4 r2=((const float4*)(rw+2*DM))[tid];
  float4 r3=((const float4*)(rw+3*DM))[tid];
  float nsq = y0*y0+y1*y1+y2*y2+y3*y3;
  float d0 = y0*r0.x+y1*r0.y+y2*r0.z+y3*r0.w;
  float d1 = y0*r1.x+y1*r1.y+y2*r1.z+y3*r1.w;
  float d2 = y0*r2.x+y1*r2.y+y2*r2.z+y3*r2.w;
  float d3 = y0*r3.x+y1*r3.y+y2*r3.z+y3*r3.w;
  float am = fmaxf(fmaxf(fabsf(y0),fabsf(y1)), fmaxf(fabsf(y2),fabsf(y3)));
  float AM = block_reduce_max256(am, red);
  float SQ = block_reduce_sum256(nsq, red);
  float D0 = block_reduce_sum256(d0, red);
  float D1 = block_reduce_sum256(d1, red);
  float D2 = block_reduce_sum256(d2, red);
  float D3 = block_reduce_sum256(d3, red);
  float qs = fmaxf(AM, 1e-12f) * (1.0f/127.0f);
  float inv = 1.0f/qs;
  char4 c;
  c.x = (signed char)__float2int_rn(y0*inv);
  c.y = (signed char)__float2int_rn(y1*inv);
  c.z = (signed char)__float2int_rn(y2*inv);
  c.w = (signed char)__float2int_rn(y3*inv);
  ((char4*)(xn8 + (size_t)t*DM))[tid] = c;
  if (tid==0){
    float n = fmaxf(sqrtf(D0*D0+D1*D1+D2*D2+D3*D3), 1e-12f);
    float h0=D0/n, h1=D1/n, h2=D2/n, h3=D3/n;
    float dot0 = 0.70710678f*(h0-h1);
    float dot1 = 0.70710678f*(h1-h2);
    float dot2 = h2;
    float dot3 = (-0.5f*h0+0.5f*h1+0.5f*h2+0.80901699f*h3)*0.8437966f;
    int ch = (int)(dot0>=0.f) + 2*(int)(dot1>=0.f) + 4*(int)(dot2>=0.f) + 8*(int)(dot3>=0.f);
    int e1 = ch & 7;
    int e2 = ((ch>>1)+1) & 7;
    if (e1==e2) e2=(e2+1)&7;
    float conf = fminf(fminf(fabsf(dot0),fabsf(dot1)), fminf(fabsf(dot2),fabsf(dot3)));
    eidx[2*t]=e1; eidx[2*t+1]=e2;
    w1o[t]=0.5f + 0.3f/(1.0f+__expf(-conf));
    sbc[t]= qs / (sqrtf(SQ*(1.0f/DM))+1e-8f);
  }
}

// ---------------- routing: histogram + offsets + scatter in ONE single-block kernel ----------------
__global__ __launch_bounds__(256) void k_route(const int* __restrict__ eidx, const float* __restrict__ sbc,
                                               int* __restrict__ tile2e, int* __restrict__ rowmap,
                                               float* __restrict__ srow, int* __restrict__ tokrow,
                                               int* __restrict__ ptot){
  __shared__ int cnt[8], pos[8];
  const int tid = threadIdx.x;
  if (tid<8) cnt[tid]=0;
  __syncthreads();
  for (int t=tid; t<TOK; t+=256){
    atomicAdd(&cnt[eidx[2*t]],1);
    atomicAdd(&cnt[eidx[2*t+1]],1);
  }
  __syncthreads();
  if (tid==0){
    int off=0;
    for (int e=0;e<8;e++){
      pos[e]=off;
      int pad = ((cnt[e]+127)>>7)<<7;
      int t0=off>>7, t1=(off+pad)>>7;
      for (int tt=t0;tt<t1;tt++) tile2e[tt]=e;
      off+=pad;
    }
    *ptot=off;
    for (int tt=off>>7; tt<PADTILES; tt++) tile2e[tt]=-1;
  }
  __syncthreads();
  for (int i=tid;i<PADROWS;i+=256){ rowmap[i]=-1; srow[i]=0.f; }
  __syncthreads();
  for (int t=tid; t<TOK; t+=256){
    int e1=eidx[2*t], e2=eidx[2*t+1];
    float s=sbc[t];
    int r1 = atomicAdd(&pos[e1],1);
    rowmap[r1]=t; srow[r1]=s; tokrow[2*t]=r1;
    int r2 = atomicAdd(&pos[e2],1);
    rowmap[r2]=t; srow[r2]=s; tokrow[2*t+1]=r2;
  }
}

// ---------------- GELU (exact) + per-row RMS normalize + i8 quant ----------------
__global__ __launch_bounds__(256) void k_gelu_rms(const u16* __restrict__ he, signed char* __restrict__ he8,
                                                  float* __restrict__ qd, const int* __restrict__ ptot){
  const int row = blockIdx.x;
  if (row >= *ptot) return;
  const u16* p = he + (size_t)row*DFF;
  const int tid=threadIdx.x;
  uint4 rw0 = ((const uint4*)p)[2*tid];
  uint4 rw1 = ((const uint4*)p)[2*tid+1];
  float v[16];
  unpack8(rw0, v); unpack8(rw1, v+8);
  float sq=0.f;
  #pragma unroll
  for (int q=0;q<16;q++){
    float xg = v[q];
    float ge = 0.5f*xg*(1.0f+erff(xg*0.70710678f));
    v[q]=ge; sq += ge*ge;
  }
  __shared__ float red[4];
  float SQ = block_reduce_sum256(sq, red);
  float s = 1.0f/(sqrtf(SQ*(1.0f/DFF))+1e-8f);
  float am = 0.f;
  #pragma unroll
  for (int q=0;q<16;q++){ v[q]*=s; am = fmaxf(am, fabsf(v[q])); }
  float AM = block_reduce_max256(am, red);
  float q8 = fmaxf(AM, 1e-12f) * (1.0f/127.0f);
  float inv = 1.0f/q8;
  union { signed char c[16]; uint4 u; } pk;
  #pragma unroll
  for (int q=0;q<16;q++) pk.c[q] = (signed char)__float2int_rn(v[q]*inv);
  ((uint4*)(he8 + (size_t)row*DFF))[tid] = pk.u;
  if (tid==0) qd[row] = q8;
}

// ---------------- combine ----------------
__global__ __launch_bounds__(256) void k_combine(const float* __restrict__ xa, const u16* __restrict__ y,
                                                 const int* __restrict__ tokrow, const float* __restrict__ w1,
                                                 float* __restrict__ out){
  const int t=blockIdx.x, tid=threadIdx.x;
  const int r1=tokrow[2*t], r2=tokrow[2*t+1];
  const float a = w1[t], bw = 1.0f-a;
  float4 xv = ((const float4*)(xa + (size_t)t*DM))[tid];
  ushort4 y1 = ((const ushort4*)(y + (size_t)r1*DM))[tid];
  ushort4 y2 = ((const ushort4*)(y + (size_t)r2*DM))[tid];
  float4 o;
  o.x = xv.x + a*b2f(y1.x) + bw*b2f(y2.x);
  o.y = xv.y + a*b2f(y1.y) + bw*b2f(y2.y);
  o.z = xv.z + a*b2f(y1.z) + bw*b2f(y2.z);
  o.w = xv.w + a*b2f(y1.w) + bw*b2f(y2.w);
  ((float4*)(out + (size_t)t*DM))[tid] = o;
}

extern "C" void kernel_launch(void* const* d_in, const int* in_sizes, int n_in,
                              void* d_out, int out_size, void* d_ws, size_t ws_size,
                              hipStream_t stream){
  (void)in_sizes; (void)n_in; (void)out_size; (void)ws_size;
  const float* x    = (const float*)d_in[0];
  const float* g1   = (const float*)d_in[1];
  const float* b1   = (const float*)d_in[2];
  const float* g2   = (const float*)d_in[3];
  const float* b2   = (const float*)d_in[4];
  const float* in_w = (const float*)d_in[5];
  const float* in_b = (const float*)d_in[6];
  const float* out_w= (const float*)d_in[7];
  const float* out_b= (const float*)d_in[8];
  const float* rw   = (const float*)d_in[9];
  const float* up_w = (const float*)d_in[10];
  const float* dn_w = (const float*)d_in[11];
  float* out = (float*)d_out;

  char* base = (char*)d_ws; size_t off=0;
  auto alloc = [&](size_t bytes)->char*{ char* p = base+off; off=(off+bytes+255)&~(size_t)255; return p; };
  u16* h      = (u16*)alloc((size_t)TOK*DM*2);
  u16* qkv    = (u16*)alloc((size_t)TOK*3072*2);
  u16* ob     = (u16*)alloc((size_t)TOK*DM*2);
  float* xattn= (float*)alloc((size_t)TOK*DM*4);
  signed char* xn8 = (signed char*)alloc((size_t)TOK*DM);
  signed char* tern8 = (signed char*)alloc((size_t)16*MATSZ);
  u16* wbf_in = (u16*)alloc((size_t)3145728*2);
  u16* wbf_out= (u16*)alloc((size_t)1048576*2);
  u16* vT     = (u16*)alloc((size_t)4*16*64*1024*2);
  u16* he     = (u16*)alloc((size_t)PADROWS*DFF*2);
  signed char* he8 = (signed char*)alloc((size_t)PADROWS*DFF);
  u16* y      = (u16*)alloc((size_t)PADROWS*DM*2);
  float* partials = (float*)alloc(8192*4);
  float* thr  = (float*)alloc(64);
  int* ptot   = (int*)alloc(64);
  int* eidx   = (int*)alloc((size_t)TOK*2*4);
  float* w1b  = (float*)alloc((size_t)TOK*4);
  float* sbc  = (float*)alloc((size_t)TOK*4);
  float* srow = (float*)alloc((size_t)PADROWS*4);
  float* qd   = (float*)alloc((size_t)PADROWS*4);
  int* tokrow = (int*)alloc((size_t)TOK*2*4);
  int* rowmap = (int*)alloc((size_t)PADROWS*4);
  int* tile2e = (int*)alloc(PADTILES*4);

  k_absum1<<<8192,256,0,stream>>>(up_w, dn_w, partials);
  k_absum2<<<1,256,0,stream>>>(partials, thr);
  k_ternarize<<<8192,256,0,stream>>>(up_w, dn_w, thr, tern8);
  k_f2b<<<3072,256,0,stream>>>(in_w, wbf_in, 786432);
  k_f2b<<<1024,256,0,stream>>>(out_w, wbf_out, 262144);
  k_ln1<<<TOK,256,0,stream>>>(x, g1, b1, h);
  k_gemm<2><<<dim3(24,32),256,0,stream>>>(h, wbf_in, 1024, 3072, in_b, nullptr, qkv, vT);
  k_attn_mfma<<<dim3(16,16,4),256,0,stream>>>(qkv, vT, ob);
  k_gemm<3><<<dim3(8,32),256,0,stream>>>(ob, wbf_out, 1024, 1024, out_b, x, xattn, nullptr);
  k_ln2_router<<<TOK,256,0,stream>>>(xattn, g2, b2, rw, xn8, eidx, w1b, sbc);
  k_route<<<1,256,0,stream>>>(eidx, sbc, tile2e, rowmap, srow, tokrow, ptot);
  k_gemm8<true><<<dim3(32,PADTILES),256,0,stream>>>(xn8, tern8, 1024, 4096,
      tile2e, rowmap, srow, he);
  k_gelu_rms<<<PADROWS,256,0,stream>>>(he, he8, qd, ptot);
  k_gemm8<false><<<dim3(8,PADTILES),256,0,stream>>>(he8, tern8 + (size_t)8*MATSZ, 4096, 1024,
      tile2e, nullptr, qd, y);
  k_combine<<<TOK,256,0,stream>>>(xattn, y, tokrow, w1b, out);
}